// Round 2
// baseline (1092.258 us; speedup 1.0000x reference)
//
#include <hip/hip_runtime.h>
#include <cstdint>
#include <cstddef>

typedef unsigned short u16;
typedef u16 u16x8 __attribute__((ext_vector_type(8)));

constexpr int B    = 4;
constexpr int CIN  = 64;
constexpr int COUT = 128;
constexpr int V    = 50000;
constexpr int KP1  = 7;
constexpr float EPS = 1e-5f;

constexpr int TV = 64;   // vertices per conv block
constexpr int RC = 32;   // r-chunk (r = k*C + c)

__device__ __forceinline__ float bf2f(u16 u) {
    return __uint_as_float(((unsigned)u) << 16);
}
__device__ __forceinline__ u16 f2bf(float f) {
    unsigned x = __float_as_uint(f);
    x += 0x7FFFu + ((x >> 16) & 1u);   // RNE
    return (u16)(x >> 16);
}

// ---- weight transpose: w[o][c][k] (f32) -> wT[k*C+c][o] (f32) ----
template<int C>
__global__ __launch_bounds__(256) void transpose_w(const float* __restrict__ w,
                                                   float* __restrict__ wT) {
    const int t = blockIdx.x * 256 + threadIdx.x;
    if (t >= KP1 * C * COUT) return;
    const int o = t & (COUT - 1);
    const int r = t >> 7;
    const int k = r / C;
    const int c = r % C;
    wT[t] = w[((size_t)o * C + c) * KP1 + k];
}

// ---- fe transpose: fe[b][c][v] (f32) -> feT[b][v][c] (bf16) ----
__global__ __launch_bounds__(256) void transpose_fe(const float* __restrict__ fe,
                                                    u16* __restrict__ feT) {
    __shared__ u16 tile[32][33];
    const int t  = threadIdx.x;
    const int tx = t & 31, ty = t >> 5;           // 32 x 8
    const int v0 = blockIdx.x * 32;
    const int c0 = blockIdx.y * 32;
    const int b  = blockIdx.z;
#pragma unroll
    for (int p = 0; p < 4; ++p) {
        const int c = c0 + ty + p * 8;
        const int v = v0 + tx;
        if (v < V) tile[ty + p * 8][tx] = f2bf(fe[((size_t)b * CIN + c) * V + v]);
    }
    __syncthreads();
#pragma unroll
    for (int p = 0; p < 4; ++p) {
        const int v = v0 + ty + p * 8;
        const int c = c0 + tx;
        if (v < V) feT[((size_t)b * V + v) * CIN + c] = tile[tx][ty + p * 8];
    }
}

// Input layouts:  0 = vertex-major bf16 [B][V][C] (ws)
//                 1 = channel-major f32 [B][C][V] (d_in fe)
//                 2 = channel-major, HIGH u16 of u32 word [B][C][V] (d_out)
// Output layouts: 0 = vertex-major bf16 [B][V][COUT] (ws)
//                 1 = channel-major f32 [B][COUT][V] (d_out)
//                 2 = HIGH u16 of word  (d_out)
//                 3 = LOW u16 of word   (d_out)
template<int C, int INL, int OUTL>
__global__ __launch_bounds__(256) void conv_kernel(const void*  __restrict__ xin_,
                                                   const float* __restrict__ wT,
                                                   const float* __restrict__ bias,
                                                   const int*   __restrict__ nbr,
                                                   void* __restrict__ out_) {
    __shared__ __align__(16) float Xl[RC][TV + 4];
    __shared__ __align__(16) float Wl[RC][COUT];

    const int t = threadIdx.x;
    constexpr int NT = (V + TV - 1) / TV;
    const int b  = blockIdx.x / NT;
    const int v0 = (blockIdx.x % NT) * TV;
    const int og = t >> 4;        // 0..15 -> 8 outputs each
    const int vg = t & 15;        // 0..15 -> 4 vertices each

    const int sv = t >> 2;              // 0..63 vertex in tile
    const int sc = (t & 3) * 8;         // 8 channels within 32-chunk
    const int v  = v0 + sv;
    const bool valid = v < V;

    float acc[8][4];
#pragma unroll
    for (int i = 0; i < 8; ++i)
#pragma unroll
        for (int j = 0; j < 4; ++j) acc[i][j] = 0.f;

    constexpr int RCH = KP1 * C / RC;
    const int wrow = t >> 3;            // 0..31
    const int wcol = (t & 7) * 16;      // 0..112

    for (int ch = 0; ch < RCH; ++ch) {
        const int k  = ch / (C / RC);
        const int c0 = (ch % (C / RC)) * RC;

        int idx = v;
        if (k > 0) idx = valid ? nbr[((size_t)b * V + v) * 6 + (k - 1)] : 0;
        float xv[8];
        if (valid) {
            if constexpr (INL == 0) {
                const u16x8 raw = *(const u16x8*)((const u16*)xin_ +
                                   ((size_t)b * V + idx) * C + c0 + sc);
#pragma unroll
                for (int j = 0; j < 8; ++j) xv[j] = bf2f(raw[j]);
            } else if constexpr (INL == 1) {
                const float* p = (const float*)xin_ + ((size_t)b * C + c0 + sc) * V + idx;
#pragma unroll
                for (int j = 0; j < 8; ++j) xv[j] = p[(size_t)j * V];
            } else {
                const unsigned* p = (const unsigned*)xin_ + ((size_t)b * C + c0 + sc) * V + idx;
#pragma unroll
                for (int j = 0; j < 8; ++j)
                    xv[j] = __uint_as_float(p[(size_t)j * V] & 0xffff0000u);
            }
        } else {
#pragma unroll
            for (int j = 0; j < 8; ++j) xv[j] = 0.f;
        }
#pragma unroll
        for (int j = 0; j < 8; ++j) Xl[sc + j][sv] = xv[j];

        const float* wp = &wT[(size_t)(ch * RC + wrow) * COUT + wcol];
        float4 w0 = *(const float4*)(wp);
        float4 w1 = *(const float4*)(wp + 4);
        float4 w2 = *(const float4*)(wp + 8);
        float4 w3 = *(const float4*)(wp + 12);
        *(float4*)&Wl[wrow][wcol]      = w0;
        *(float4*)&Wl[wrow][wcol + 4]  = w1;
        *(float4*)&Wl[wrow][wcol + 8]  = w2;
        *(float4*)&Wl[wrow][wcol + 12] = w3;

        __syncthreads();

#pragma unroll 8
        for (int rr = 0; rr < RC; ++rr) {
            const float4 x4 = *(const float4*)&Xl[rr][vg * 4];
            const float4 wa = *(const float4*)&Wl[rr][og * 8];
            const float4 wb = *(const float4*)&Wl[rr][og * 8 + 4];
            const float wv[8] = {wa.x, wa.y, wa.z, wa.w, wb.x, wb.y, wb.z, wb.w};
            const float xs[4] = {x4.x, x4.y, x4.z, x4.w};
#pragma unroll
            for (int i = 0; i < 8; ++i)
#pragma unroll
                for (int j = 0; j < 4; ++j)
                    acc[i][j] += wv[i] * xs[j];
        }
        __syncthreads();
    }

    float bo[8];
#pragma unroll
    for (int i = 0; i < 8; ++i) bo[i] = bias[og * 8 + i];

    if constexpr (OUTL == 0) {            // vertex-major bf16 (ws)
        u16* po = (u16*)out_;
#pragma unroll
        for (int j = 0; j < 4; ++j) {
            const int vv = v0 + vg * 4 + j;
            if (vv < V) {
                u16x8 pk;
#pragma unroll
                for (int i = 0; i < 8; ++i) pk[i] = f2bf(acc[i][j] + bo[i]);
                *(u16x8*)&po[((size_t)b * V + vv) * COUT + og * 8] = pk;
            }
        }
    } else if constexpr (OUTL == 1) {     // channel-major f32 (d_out)
        float* po = (float*)out_;
        const int vb = v0 + vg * 4;
        if (vb < V) {
#pragma unroll
            for (int i = 0; i < 8; ++i) {
                float4 st = make_float4(acc[i][0] + bo[i], acc[i][1] + bo[i],
                                        acc[i][2] + bo[i], acc[i][3] + bo[i]);
                *(float4*)&po[((size_t)b * COUT + og * 8 + i) * V + vb] = st;
            }
        }
    } else {                              // packed u16 halves of d_out words
        u16* po = (u16*)out_;
        constexpr int half = (OUTL == 2) ? 1 : 0;
#pragma unroll
        for (int i = 0; i < 8; ++i) {
#pragma unroll
            for (int j = 0; j < 4; ++j) {
                const int vv = v0 + vg * 4 + j;
                if (vv < V) {
                    const size_t wd = ((size_t)b * COUT + og * 8 + i) * V + vv;
                    po[2 * wd + half] = f2bf(acc[i][j] + bo[i]);
                }
            }
        }
    }
}

// ---- stats over vertex-major bf16 [B][V][128] (ws): two-stage ----
__global__ __launch_bounds__(256) void stats1_partial(const u16* __restrict__ x,
                                                      float2* __restrict__ P) {
    const int t = threadIdx.x;
    const int s = blockIdx.x & 63;
    const int b = blockIdx.x >> 6;
    const int o = t & 127;
    const int half = t >> 7;
    float sum = 0.f, sq = 0.f;
    for (int v = 2 * s + half; v < V; v += 128) {
        const float f = bf2f(x[((size_t)b * V + v) * COUT + o]);
        sum += f; sq += f * f;
    }
    __shared__ float2 red[256];
    red[t] = make_float2(sum, sq);
    __syncthreads();
    if (t < 128) {
        const float2 o2 = red[t + 128];
        P[((size_t)b * 64 + s) * COUT + o] = make_float2(sum + o2.x, sq + o2.y);
    }
}

__global__ __launch_bounds__(256) void finalize1(const float2* __restrict__ P,
                                                 float2* __restrict__ S) {
    const int id = blockIdx.x * 256 + threadIdx.x;
    if (id >= B * COUT) return;
    float sum = 0.f, sq = 0.f;
    const int b = id >> 7, o = id & 127;
    for (int s = 0; s < 64; ++s) {
        const float2 p = P[((size_t)b * 64 + s) * COUT + o];
        sum += p.x; sq += p.y;
    }
    const float m = sum / V;
    const float var = sq / V - m * m;
    S[id] = make_float2(m, rsqrtf(var + EPS));
}

// ---- normalize + relu in place, vertex-major bf16 (ws) ----
__global__ __launch_bounds__(256) void norm1(u16* __restrict__ x,
                                             const float2* __restrict__ S) {
    const size_t e = ((size_t)blockIdx.x * 256 + threadIdx.x) * 8;
    if (e >= (size_t)B * V * COUT) return;
    const int b  = (int)(e / ((size_t)V * COUT));
    const int o0 = (int)(e & 127);
    u16x8 vv = *(u16x8*)&x[e];
#pragma unroll
    for (int j = 0; j < 8; ++j) {
        const float2 s = S[b * COUT + o0 + j];
        float f = (bf2f(vv[j]) - s.x) * s.y;
        vv[j] = f2bf(fmaxf(f, 0.f));
    }
    *(u16x8*)&x[e] = vv;
}

__device__ __forceinline__ void block_reduce_stats(float sum, float sq, float2* S, int row) {
    __shared__ float2 red[256];
    red[threadIdx.x] = make_float2(sum, sq);
    __syncthreads();
    for (int w = 128; w > 0; w >>= 1) {
        if (threadIdx.x < w) {
            red[threadIdx.x].x += red[threadIdx.x + w].x;
            red[threadIdx.x].y += red[threadIdx.x + w].y;
        }
        __syncthreads();
    }
    if (threadIdx.x == 0) {
        const float m = red[0].x / V;
        const float var = red[0].y / V - m * m;
        S[row] = make_float2(m, rsqrtf(var + EPS));
    }
}

// ---- stats over channel-major f32 rows [B*128][V] (d_out) ----
__global__ __launch_bounds__(256) void stats_f32(const float* __restrict__ y,
                                                 float2* __restrict__ S) {
    const int row = blockIdx.x;
    const float4* p = (const float4*)(y + (size_t)row * V);
    float sum = 0.f, sq = 0.f;
    for (int i = threadIdx.x; i < V / 4; i += 256) {
        const float4 f = p[i];
        sum += f.x + f.y + f.z + f.w;
        sq  += f.x * f.x + f.y * f.y + f.z * f.z + f.w * f.w;
    }
    block_reduce_stats(sum, sq, S, row);
}

// ---- stats over one u16 half of d_out words, per row ----
template<int HI>
__global__ __launch_bounds__(256) void stats_half(const unsigned* __restrict__ y,
                                                  float2* __restrict__ S) {
    const int row = blockIdx.x;
    const uint4* p = (const uint4*)(y + (size_t)row * V);
    float sum = 0.f, sq = 0.f;
    for (int i = threadIdx.x; i < V / 4; i += 256) {
        const uint4 w = p[i];
        const unsigned ws4[4] = {w.x, w.y, w.z, w.w};
#pragma unroll
        for (int j = 0; j < 4; ++j) {
            const float f = __uint_as_float(HI ? (ws4[j] & 0xffff0000u) : (ws4[j] << 16));
            sum += f; sq += f * f;
        }
    }
    block_reduce_stats(sum, sq, S, row);
}

// ---- normalize + relu on HIGH halves of d_out words, in place ----
__global__ __launch_bounds__(256) void norm_hi(unsigned* __restrict__ y,
                                               const float2* __restrict__ S) {
    const size_t wi = ((size_t)blockIdx.x * 256 + threadIdx.x) * 4;
    const int row = (int)(wi / V);
    const float2 s = S[row];
    uint4 w = *(uint4*)&y[wi];
    unsigned ws4[4] = {w.x, w.y, w.z, w.w};
#pragma unroll
    for (int j = 0; j < 4; ++j) {
        float f = (__uint_as_float(ws4[j] & 0xffff0000u) - s.x) * s.y;
        f = fmaxf(f, 0.f);
        ws4[j] = (ws4[j] & 0xffffu) | ((unsigned)f2bf(f) << 16);
    }
    w.x = ws4[0]; w.y = ws4[1]; w.z = ws4[2]; w.w = ws4[3];
    *(uint4*)&y[wi] = w;
}

// ---- final (packed path): word -> relu((lo-m)*inv + hi) as f32, in place ----
__global__ __launch_bounds__(256) void final_words(unsigned* __restrict__ y,
                                                   const float2* __restrict__ S) {
    const size_t wi = ((size_t)blockIdx.x * 256 + threadIdx.x) * 4;
    const int row = (int)(wi / V);
    const float2 s = S[row];
    uint4 w = *(uint4*)&y[wi];
    const unsigned ws4[4] = {w.x, w.y, w.z, w.w};
    float4 o;
    float* op = &o.x;
#pragma unroll
    for (int j = 0; j < 4; ++j) {
        const float y2 = __uint_as_float(ws4[j] << 16);
        const float x1 = __uint_as_float(ws4[j] & 0xffff0000u);
        op[j] = fmaxf((y2 - s.x) * s.y + x1, 0.f);
    }
    *(float4*)&y[wi] = o;
}

// ---- final (ws path): y f32 CM in place; x1 bf16 VM staged via LDS ----
__global__ __launch_bounds__(256) void final_mix(float* __restrict__ y,
                                                 const u16* __restrict__ x1,
                                                 const float2* __restrict__ S) {
    __shared__ float tile[64][33];
    const int t  = threadIdx.x;
    const int v0 = blockIdx.x * 64;
    const int o0 = blockIdx.y * 32;
    const int b  = blockIdx.z;
    const int j  = t & 31;
    const int i0 = t >> 5;
#pragma unroll
    for (int p = 0; p < 8; ++p) {
        const int i = i0 + p * 8;
        const int v = v0 + i;
        tile[i][j] = (v < V) ? bf2f(x1[((size_t)b * V + v) * COUT + o0 + j]) : 0.f;
    }
    __syncthreads();
    const int vl  = t & 63;
    const int v   = v0 + vl;
    const int oo0 = t >> 6;  // 0..3
    if (v < V) {
#pragma unroll
        for (int p = 0; p < 8; ++p) {
            const int oo = oo0 + p * 4;
            const int o  = o0 + oo;
            const size_t idx = ((size_t)b * COUT + o) * V + v;
            const float2 s = S[b * COUT + o];
            const float f = (y[idx] - s.x) * s.y + tile[vl][oo];
            y[idx] = fmaxf(f, 0.f);
        }
    }
}

extern "C" void kernel_launch(void* const* d_in, const int* in_sizes, int n_in,
                              void* d_out, int out_size, void* d_ws, size_t ws_size,
                              hipStream_t stream) {
    const float* fe  = (const float*)d_in[0];
    const int*   nbr = (const int*)d_in[1];
    const float* w1  = (const float*)d_in[2];
    const float* b1  = (const float*)d_in[3];
    const float* w2  = (const float*)d_in[4];
    const float* b2  = (const float*)d_in[5];
    float*    outf = (float*)d_out;
    unsigned* outw = (unsigned*)d_out;
    char* ws = (char*)d_ws;

    const size_t feT_b = (size_t)B * V * CIN * 2;     // 25.6 MB
    const size_t x1_b  = (size_t)B * V * COUT * 2;    // 51.2 MB
    const size_t wT1_b = (size_t)KP1 * CIN * COUT * 4;
    const size_t wT2_b = (size_t)KP1 * COUT * COUT * 4;
    const size_t P1_b  = (size_t)B * 64 * COUT * 8;
    const size_t S_b   = (size_t)B * COUT * 8;
    const size_t base  = wT1_b + wT2_b + 2 * S_b;

    bool useA = false, useB = false;
    if      (ws_size >= base + P1_b + x1_b + feT_b) { useA = true; useB = true; }
    else if (ws_size >= base + P1_b + x1_b)         { useB = true; }
    else if (ws_size >= base + feT_b)               { useA = true; }
    else if (ws_size >= base)                       { /* packed-only */ }
    else return;

    size_t off = 0;
    float*  wT1 = (float*)(ws + off);  off += wT1_b;
    float*  wT2 = (float*)(ws + off);  off += wT2_b;
    float2* S1  = (float2*)(ws + off); off += S_b;
    float2* S2  = (float2*)(ws + off); off += S_b;
    float2* P1 = nullptr; u16* x1 = nullptr; u16* feT = nullptr;
    if (useB) {
        P1 = (float2*)(ws + off); off += P1_b;
        x1 = (u16*)(ws + off);    off += x1_b;
    }
    if (useA) { feT = (u16*)(ws + off); off += feT_b; }

    transpose_w<CIN> <<<(KP1 * CIN  * COUT + 255) / 256, 256, 0, stream>>>(w1, wT1);
    transpose_w<COUT><<<(KP1 * COUT * COUT + 255) / 256, 256, 0, stream>>>(w2, wT2);
    if (useA) {
        dim3 gt((V + 31) / 32, CIN / 32, B);
        transpose_fe<<<gt, 256, 0, stream>>>(fe, feT);
    }

    constexpr int NT = (V + TV - 1) / TV;   // 782
    const int NW = (int)((size_t)B * V * COUT / 4 / 256);   // 25000 word-blocks

    if (useB) {
        if (useA) conv_kernel<CIN, 0, 0><<<B * NT, 256, 0, stream>>>(feT, wT1, b1, nbr, x1);
        else      conv_kernel<CIN, 1, 0><<<B * NT, 256, 0, stream>>>(fe,  wT1, b1, nbr, x1);
        stats1_partial<<<B * 64, 256, 0, stream>>>(x1, P1);
        finalize1<<<2, 256, 0, stream>>>(P1, S1);
        norm1<<<(int)((size_t)B * V * COUT / 8 / 256), 256, 0, stream>>>(x1, S1);

        conv_kernel<COUT, 0, 1><<<B * NT, 256, 0, stream>>>(x1, wT2, b2, nbr, outf);
        stats_f32<<<B * COUT, 256, 0, stream>>>(outf, S2);
        dim3 gf(NT, COUT / 32, B);
        final_mix<<<gf, 256, 0, stream>>>(outf, x1, S2);
    } else {
        if (useA) conv_kernel<CIN, 0, 2><<<B * NT, 256, 0, stream>>>(feT, wT1, b1, nbr, outw);
        else      conv_kernel<CIN, 1, 2><<<B * NT, 256, 0, stream>>>(fe,  wT1, b1, nbr, outw);
        stats_half<1><<<B * COUT, 256, 0, stream>>>(outw, S1);
        norm_hi<<<NW, 256, 0, stream>>>(outw, S1);

        conv_kernel<COUT, 2, 3><<<B * NT, 256, 0, stream>>>(outw, wT2, b2, nbr, outw);
        stats_half<0><<<B * COUT, 256, 0, stream>>>(outw, S2);
        final_words<<<NW, 256, 0, stream>>>(outw, S2);
    }
}

// Round 3
// 371.117 us; speedup vs baseline: 2.9432x; 2.9432x over previous
//
#include <hip/hip_runtime.h>
#include <cstdint>
#include <cstddef>

typedef unsigned short u16;
typedef u16 u16x8 __attribute__((ext_vector_type(8)));
typedef u16 u16x4 __attribute__((ext_vector_type(4)));
typedef _Float16 f16x8 __attribute__((ext_vector_type(8)));
typedef float f32x4 __attribute__((ext_vector_type(4)));

constexpr int B    = 4;
constexpr int CIN  = 64;
constexpr int COUT = 128;
constexpr int V    = 50000;
constexpr int KP1  = 7;
constexpr float EPS = 1e-5f;

constexpr int BN  = 128;                 // vertices per conv block
constexpr int NT  = (V + BN - 1) / BN;   // 391
constexpr int NT64 = (V + 63) / 64;      // 782 (final_mix tiles)

__device__ __forceinline__ u16 f2h(float f) {
    _Float16 h = (_Float16)f;
    return __builtin_bit_cast(u16, h);
}
__device__ __forceinline__ float h2f(u16 s) {
    return (float)__builtin_bit_cast(_Float16, s);
}

// ---- W -> fragment-ordered fp16: wF[ch][ot][lane][j] = W[o][r],
//      o = ot*16 + (lane&15), r = ch*32 + (lane>>4)*8 + j, r=k*C+c ----
template<int C>
__global__ __launch_bounds__(256) void prep_wf(const float* __restrict__ w,
                                               u16* __restrict__ wF) {
    constexpr int RCH = KP1 * C / 32;
    const int g = blockIdx.x * 256 + threadIdx.x;
    if (g >= RCH * 8 * 64) return;
    const int l  = g & 63;
    const int m  = (g >> 6) & 7;
    const int ch = g >> 9;
    const int k  = ch / (C / 32);
    const int c0 = (ch % (C / 32)) * 32;
    const int o  = m * 16 + (l & 15);
    u16x8 out;
#pragma unroll
    for (int j = 0; j < 8; ++j) {
        const int c = c0 + (l >> 4) * 8 + j;
        out[j] = f2h(w[((size_t)o * C + c) * KP1 + k]);
    }
    *(u16x8*)&wF[(size_t)g * 8] = out;
}

// ---- fe transpose: fe[b][c][v] (f32) -> feT[b][v][c] (f16) ----
__global__ __launch_bounds__(256) void transpose_fe(const float* __restrict__ fe,
                                                    u16* __restrict__ feT) {
    __shared__ u16 tile[32][33];
    const int t  = threadIdx.x;
    const int tx = t & 31, ty = t >> 5;           // 32 x 8
    const int v0 = blockIdx.x * 32;
    const int c0 = blockIdx.y * 32;
    const int b  = blockIdx.z;
#pragma unroll
    for (int p = 0; p < 4; ++p) {
        const int c = c0 + ty + p * 8;
        const int v = v0 + tx;
        if (v < V) tile[ty + p * 8][tx] = f2h(fe[((size_t)b * CIN + c) * V + v]);
    }
    __syncthreads();
#pragma unroll
    for (int p = 0; p < 4; ++p) {
        const int v = v0 + ty + p * 8;
        const int c = c0 + tx;
        if (v < V) feT[((size_t)b * V + v) * CIN + c] = tile[tx][ty + p * 8];
    }
}

// ---- MFMA gather-conv: y[o][v] = sum_r W[o][r] X[r][v] ----
// INL: 0 = vertex-major f16 [B][V][C]; 1 = channel-major f32 [B][C][V] (fe direct)
// OUTL: 0 = vertex-major f16 [B][V][COUT] (ws x1); 1 = channel-major f32 (d_out)
template<int C, int INL, int OUTL>
__global__ __launch_bounds__(256) void conv_mfma(const void* __restrict__ xin_,
                                                 const u16*  __restrict__ wF,
                                                 const float* __restrict__ bias,
                                                 const int*  __restrict__ nbr,
                                                 void* __restrict__ out_) {
    constexpr int RCH  = KP1 * C / 32;   // 14 or 28
    constexpr int KSH  = (C == 64) ? 1 : 2;      // log2(chunks per k)
    constexpr int KMSK = (C / 32) - 1;
    __shared__ __align__(16) u16 Xl[2][BN][40];  // 80B row stride: 16B-aligned, <=2-way banks

    const int t  = threadIdx.x;
    const int b  = blockIdx.x / NT;
    const int v0 = (blockIdx.x % NT) * BN;
    const int w  = t >> 6;
    const int l  = t & 63;
    const int wo = (w & 1) * 64;         // wave o-offset
    const int wv = (w >> 1) * 64;        // wave v-offset

    // staging role: thread covers v-rows (t>>2) and (t>>2)+64, c-segment (t&3)*8
    const int svA = t >> 2, svB = svA + 64;
    const int seg = t & 3;
    const int vA = v0 + svA, vB = v0 + svB;
    const bool okA = vA < V, okB = vB < V;

    f32x4 acc[4][4];
#pragma unroll
    for (int m = 0; m < 4; ++m)
#pragma unroll
        for (int n = 0; n < 4; ++n) acc[m][n] = (f32x4)0.f;

    auto stage_load = [&](int ch, u16x8& rA, u16x8& rB) {
        const int k  = ch >> KSH;
        const int c0 = (ch & KMSK) * 32;
        int iA = okA ? vA : 0, iB = okB ? vB : 0;
        if (k > 0) {
            iA = okA ? nbr[((size_t)b * V + vA) * 6 + (k - 1)] : 0;
            iB = okB ? nbr[((size_t)b * V + vB) * 6 + (k - 1)] : 0;
        }
        if constexpr (INL == 0) {
            const u16* x = (const u16*)xin_;
            rA = *(const u16x8*)&x[((size_t)b * V + iA) * C + c0 + seg * 8];
            rB = *(const u16x8*)&x[((size_t)b * V + iB) * C + c0 + seg * 8];
        } else {
            const float* x = (const float*)xin_;
            const float* pA = &x[((size_t)b * C + c0 + seg * 8) * V + iA];
            const float* pB = &x[((size_t)b * C + c0 + seg * 8) * V + iB];
#pragma unroll
            for (int j = 0; j < 8; ++j) {
                rA[j] = f2h(pA[(size_t)j * V]);
                rB[j] = f2h(pB[(size_t)j * V]);
            }
        }
    };

    u16x8 rA, rB;
    stage_load(0, rA, rB);
    *(u16x8*)&Xl[0][svA][seg * 8] = rA;
    *(u16x8*)&Xl[0][svB][seg * 8] = rB;

    for (int ch = 0; ch < RCH; ++ch) {
        const int nxt = (ch + 1 < RCH) ? ch + 1 : ch;
        stage_load(nxt, rA, rB);                    // prefetch next chunk (global)
        f16x8 af[4];
#pragma unroll
        for (int m = 0; m < 4; ++m)                 // A frags: coalesced 16B, L1/L2-hit
            af[m] = *(const f16x8*)&wF[(((size_t)ch * 8 + (wo >> 4) + m) * 64 + l) * 8];
        __syncthreads();                            // buf[ch&1] writes visible
        f16x8 bf[4];
#pragma unroll
        for (int n = 0; n < 4; ++n)
            bf[n] = *(const f16x8*)&Xl[ch & 1][wv + n * 16 + (l & 15)][(l >> 4) * 8];
#pragma unroll
        for (int m = 0; m < 4; ++m)
#pragma unroll
            for (int n = 0; n < 4; ++n)
                acc[m][n] = __builtin_amdgcn_mfma_f32_16x16x32_f16(af[m], bf[n], acc[m][n], 0, 0, 0);
        *(u16x8*)&Xl[(ch + 1) & 1][svA][seg * 8] = rA;   // safe: all waves past barrier
        *(u16x8*)&Xl[(ch + 1) & 1][svB][seg * 8] = rB;
    }

    // D layout: o = wo + m*16 + (l>>4)*4 + q ; v = v0 + wv + n*16 + (l&15)
    if constexpr (OUTL == 0) {
        u16* po = (u16*)out_;
#pragma unroll
        for (int n = 0; n < 4; ++n) {
            const int v = v0 + wv + n * 16 + (l & 15);
            if (v < V) {
#pragma unroll
                for (int m = 0; m < 4; ++m) {
                    const int o = wo + m * 16 + ((l >> 4) << 2);
                    u16x4 pk;
#pragma unroll
                    for (int q = 0; q < 4; ++q) pk[q] = f2h(acc[m][n][q] + bias[o + q]);
                    *(u16x4*)&po[((size_t)b * V + v) * COUT + o] = pk;
                }
            }
        }
    } else {
        float* po = (float*)out_;
#pragma unroll
        for (int m = 0; m < 4; ++m) {
            const int o = wo + m * 16 + ((l >> 4) << 2);
#pragma unroll
            for (int q = 0; q < 4; ++q) {
                const float bq = bias[o + q];
#pragma unroll
                for (int n = 0; n < 4; ++n) {
                    const int v = v0 + wv + n * 16 + (l & 15);
                    if (v < V) po[((size_t)(b * COUT + o + q)) * V + v] = acc[m][n][q] + bq;
                }
            }
        }
    }
}

// ---- stats over vertex-major f16 y1 [B][V][128] (ws): two-stage ----
__global__ __launch_bounds__(256) void stats1_partial(const u16* __restrict__ x,
                                                      float2* __restrict__ P) {
    const int t = threadIdx.x;
    const int s = blockIdx.x & 63;
    const int b = blockIdx.x >> 6;
    const int o = t & 127;
    const int half = t >> 7;
    float sum = 0.f, sq = 0.f;
    for (int v = 2 * s + half; v < V; v += 128) {
        const float f = h2f(x[((size_t)b * V + v) * COUT + o]);
        sum += f; sq += f * f;
    }
    __shared__ float2 red[256];
    red[t] = make_float2(sum, sq);
    __syncthreads();
    if (t < 128) {
        const float2 o2 = red[t + 128];
        P[((size_t)b * 64 + s) * COUT + o] = make_float2(sum + o2.x, sq + o2.y);
    }
}

__global__ __launch_bounds__(256) void finalize1(const float2* __restrict__ P,
                                                 float2* __restrict__ S) {
    const int id = blockIdx.x * 256 + threadIdx.x;
    if (id >= B * COUT) return;
    float sum = 0.f, sq = 0.f;
    const int b = id >> 7, o = id & 127;
    for (int s = 0; s < 64; ++s) {
        const float2 p = P[((size_t)b * 64 + s) * COUT + o];
        sum += p.x; sq += p.y;
    }
    const float m = sum / V;
    const float var = sq / V - m * m;
    S[id] = make_float2(m, rsqrtf(var + EPS));
}

// ---- normalize + relu in place, vertex-major f16 (ws) ----
__global__ __launch_bounds__(256) void norm1(u16* __restrict__ x,
                                             const float2* __restrict__ S) {
    const size_t e = ((size_t)blockIdx.x * 256 + threadIdx.x) * 8;
    if (e >= (size_t)B * V * COUT) return;
    const int b  = (int)(e / ((size_t)V * COUT));
    const int o0 = (int)(e & 127);
    u16x8 vv = *(u16x8*)&x[e];
#pragma unroll
    for (int j = 0; j < 8; ++j) {
        const float2 s = S[b * COUT + o0 + j];
        float f = (h2f(vv[j]) - s.x) * s.y;
        vv[j] = f2h(fmaxf(f, 0.f));
    }
    *(u16x8*)&x[e] = vv;
}

// ---- stats over channel-major f32 rows [B*128][V] (d_out) ----
__global__ __launch_bounds__(256) void stats_f32(const float* __restrict__ y,
                                                 float2* __restrict__ S) {
    const int row = blockIdx.x;
    const float4* p = (const float4*)(y + (size_t)row * V);
    float sum = 0.f, sq = 0.f;
    for (int i = threadIdx.x; i < V / 4; i += 256) {
        const float4 f = p[i];
        sum += f.x + f.y + f.z + f.w;
        sq  += f.x * f.x + f.y * f.y + f.z * f.z + f.w * f.w;
    }
    __shared__ float2 red[256];
    red[threadIdx.x] = make_float2(sum, sq);
    __syncthreads();
    for (int w = 128; w > 0; w >>= 1) {
        if (threadIdx.x < w) {
            red[threadIdx.x].x += red[threadIdx.x + w].x;
            red[threadIdx.x].y += red[threadIdx.x + w].y;
        }
        __syncthreads();
    }
    if (threadIdx.x == 0) {
        const float m = red[0].x / V;
        const float var = red[0].y / V - m * m;
        S[row] = make_float2(m, rsqrtf(var + EPS));
    }
}

// ---- final: out = relu((y2 - m)*inv + x1) in place on channel-major f32 d_out ----
__global__ __launch_bounds__(256) void final_mix(float* __restrict__ y,
                                                 const u16* __restrict__ x1,
                                                 const float2* __restrict__ S) {
    __shared__ float tile[64][33];
    const int t  = threadIdx.x;
    const int v0 = blockIdx.x * 64;
    const int o0 = blockIdx.y * 32;
    const int b  = blockIdx.z;
    const int j  = t & 31;
    const int i0 = t >> 5;
#pragma unroll
    for (int p = 0; p < 8; ++p) {
        const int i = i0 + p * 8;
        const int v = v0 + i;
        tile[i][j] = (v < V) ? h2f(x1[((size_t)b * V + v) * COUT + o0 + j]) : 0.f;
    }
    __syncthreads();
    const int vl  = t & 63;
    const int v   = v0 + vl;
    const int oo0 = t >> 6;  // 0..3
    if (v < V) {
#pragma unroll
        for (int p = 0; p < 8; ++p) {
            const int oo = oo0 + p * 4;
            const int o  = o0 + oo;
            const size_t idx = ((size_t)b * COUT + o) * V + v;
            const float2 s = S[b * COUT + o];
            const float f = (y[idx] - s.x) * s.y + tile[vl][oo];
            y[idx] = fmaxf(f, 0.f);
        }
    }
}

extern "C" void kernel_launch(void* const* d_in, const int* in_sizes, int n_in,
                              void* d_out, int out_size, void* d_ws, size_t ws_size,
                              hipStream_t stream) {
    const float* fe  = (const float*)d_in[0];
    const int*   nbr = (const int*)d_in[1];
    const float* w1  = (const float*)d_in[2];
    const float* b1  = (const float*)d_in[3];
    const float* w2  = (const float*)d_in[4];
    const float* b2  = (const float*)d_in[5];
    float* outf = (float*)d_out;
    char*  ws   = (char*)d_ws;

    constexpr size_t wF1_b = (size_t)(KP1 * CIN  / 32) * 8 * 64 * 8 * 2;  // 112 KB
    constexpr size_t wF2_b = (size_t)(KP1 * COUT / 32) * 8 * 64 * 8 * 2;  // 224 KB
    constexpr size_t S_b   = (size_t)B * COUT * 8;
    constexpr size_t P1_b  = (size_t)B * 64 * COUT * 8;
    constexpr size_t x1_b  = (size_t)B * V * COUT * 2;   // 51.2 MB
    constexpr size_t feT_b = (size_t)B * V * CIN * 2;    // 25.6 MB
    const size_t base = wF1_b + wF2_b + 2 * S_b + P1_b;

    if (ws_size < base + x1_b) return;                   // (known to fit)
    const bool useA = (ws_size >= base + x1_b + feT_b);

    size_t off = 0;
    u16*    wF1 = (u16*)(ws + off);    off += wF1_b;
    u16*    wF2 = (u16*)(ws + off);    off += wF2_b;
    float2* S1  = (float2*)(ws + off); off += S_b;
    float2* S2  = (float2*)(ws + off); off += S_b;
    float2* P1  = (float2*)(ws + off); off += P1_b;
    u16*    x1  = (u16*)(ws + off);    off += x1_b;
    u16*    feT = nullptr;
    if (useA) { feT = (u16*)(ws + off); off += feT_b; }

    prep_wf<CIN> <<<(KP1 * CIN  / 32) * 8 * 64 / 256, 256, 0, stream>>>(w1, wF1);
    prep_wf<COUT><<<(KP1 * COUT / 32) * 8 * 64 / 256, 256, 0, stream>>>(w2, wF2);

    if (useA) {
        dim3 gt((V + 31) / 32, CIN / 32, B);
        transpose_fe<<<gt, 256, 0, stream>>>(fe, feT);
        conv_mfma<CIN, 0, 0><<<B * NT, 256, 0, stream>>>(feT, wF1, b1, nbr, x1);
    } else {
        conv_mfma<CIN, 1, 0><<<B * NT, 256, 0, stream>>>(fe,  wF1, b1, nbr, x1);
    }

    stats1_partial<<<B * 64, 256, 0, stream>>>(x1, P1);
    finalize1<<<2, 256, 0, stream>>>(P1, S1);
    norm1<<<(int)((size_t)B * V * COUT / 8 / 256), 256, 0, stream>>>(x1, S1);

    conv_mfma<COUT, 0, 1><<<B * NT, 256, 0, stream>>>(x1, wF2, b2, nbr, outf);

    stats_f32<<<B * COUT, 256, 0, stream>>>(outf, S2);
    dim3 gf(NT64, COUT / 32, B);
    final_mix<<<gf, 256, 0, stream>>>(outf, x1, S2);
}

// Round 5
// 338.905 us; speedup vs baseline: 3.2229x; 1.0950x over previous
//
#include <hip/hip_runtime.h>
#include <cstdint>
#include <cstddef>
#include <utility>

typedef unsigned short u16;
typedef u16 u16x8 __attribute__((ext_vector_type(8)));
typedef u16 u16x4 __attribute__((ext_vector_type(4)));
typedef _Float16 f16x8 __attribute__((ext_vector_type(8)));
typedef float f32x4 __attribute__((ext_vector_type(4)));

constexpr int B    = 4;
constexpr int CIN  = 64;
constexpr int COUT = 128;
constexpr int V    = 50000;
constexpr int KP1  = 7;
constexpr float EPS = 1e-5f;

constexpr int BN  = 64;                  // vertices per conv block
constexpr int NT  = (V + BN - 1) / BN;   // 782
constexpr int NTP = 784;                 // padded tile stride for P
constexpr int NT64 = (V + 63) / 64;      // 782 (final_mix tiles)

__device__ __forceinline__ u16 f2h(float f) {
    _Float16 h = (_Float16)f;
    return __builtin_bit_cast(u16, h);
}
__device__ __forceinline__ float h2f(u16 s) {
    return (float)__builtin_bit_cast(_Float16, s);
}

template<int... Is, typename F>
__device__ __forceinline__ void static_for_impl(F&& f, std::integer_sequence<int, Is...>) {
    (f(std::integral_constant<int, Is>{}), ...);
}
template<int N, typename F>
__device__ __forceinline__ void static_for(F&& f) {
    static_for_impl(f, std::make_integer_sequence<int, N>{});
}

// ---- W -> fragment-ordered fp16: wF[ch][mfrag][lane][j] = W[o][r],
//      o = mfrag*16 + (lane&15), r = ch*32 + (lane>>4)*8 + j, r = k*C+c ----
template<int C>
__global__ __launch_bounds__(256) void prep_wf(const float* __restrict__ w,
                                               u16* __restrict__ wF) {
    constexpr int RCH = KP1 * C / 32;
    const int g = blockIdx.x * 256 + threadIdx.x;
    if (g >= RCH * 8 * 64) return;
    const int l  = g & 63;
    const int m  = (g >> 6) & 7;
    const int ch = g >> 9;
    const int k  = ch / (C / 32);
    const int c0 = (ch % (C / 32)) * 32;
    const int o  = m * 16 + (l & 15);
    u16x8 out;
#pragma unroll
    for (int j = 0; j < 8; ++j) {
        const int c = c0 + (l >> 4) * 8 + j;
        out[j] = f2h(w[((size_t)o * C + c) * KP1 + k]);
    }
    *(u16x8*)&wF[(size_t)g * 8] = out;
}

// ---- fe transpose: fe[b][c][v] (f32) -> feT[b][v][c] (f16) ----
__global__ __launch_bounds__(256) void transpose_fe(const float* __restrict__ fe,
                                                    u16* __restrict__ feT) {
    __shared__ u16 tile[32][33];
    const int t  = threadIdx.x;
    const int tx = t & 31, ty = t >> 5;           // 32 x 8
    const int v0 = blockIdx.x * 32;
    const int c0 = blockIdx.y * 32;
    const int b  = blockIdx.z;
#pragma unroll
    for (int p = 0; p < 4; ++p) {
        const int c = c0 + ty + p * 8;
        const int v = v0 + tx;
        if (v < V) tile[ty + p * 8][tx] = f2h(fe[((size_t)b * CIN + c) * V + v]);
    }
    __syncthreads();
#pragma unroll
    for (int p = 0; p < 4; ++p) {
        const int v = v0 + ty + p * 8;
        const int c = c0 + tx;
        if (v < V) feT[((size_t)b * V + v) * CIN + c] = tile[tx][ty + p * 8];
    }
}

// ---- MFMA gather-conv, NO LDS / NO barriers in main loop ----
// Block = 128o x 64v, 4 waves in 2x2: wave tile 64o x 32v.
// B-frags loaded straight from global (gather == fragment layout).
// INL:  0 = vertex-major f16 [B][V][C]; 1 = channel-major f32 [B][C][V]
// OUTL: 0 = vertex-major f16 [B][V][COUT] (ws); 1 = channel-major f32 (d_out)
// STATS: write per-(b,o,tile) partial (sum, sumsq) of y=conv+bias to P
template<int C, int INL, int OUTL, int STATS>
__global__ __launch_bounds__(256, 4) void conv_mfma(const void* __restrict__ xin_,
                                                    const u16*  __restrict__ wF,
                                                    const float* __restrict__ bias,
                                                    const int*  __restrict__ nbr,
                                                    void* __restrict__ out_,
                                                    float2* __restrict__ P) {
    constexpr int RCH  = KP1 * C / 32;   // 14 or 28
    constexpr int KSH  = (C == 64) ? 1 : 2;
    constexpr int KMSK = (C / 32) - 1;
    __shared__ float2 Sred[4][64];

    const int t    = threadIdx.x;
    const int b    = blockIdx.x / NT;
    const int tile = blockIdx.x % NT;
    const int v0   = tile * BN;
    const int w    = t >> 6;
    const int l    = t & 63;
    const int wo   = (w & 1) * 64;       // wave o-offset
    const int wv   = (w >> 1) * 32;      // wave v-offset
    const int seg  = (l >> 4) * 8;       // channel sub-offset within 32-chunk

    // hoist all neighbor indices (static indexing only -> stays in VGPRs)
    int vn[2]; bool ok[2]; int idxN[2][KP1];
#pragma unroll
    for (int n = 0; n < 2; ++n) {
        vn[n] = v0 + wv + n * 16 + (l & 15);
        ok[n] = vn[n] < V;
        const int vc = ok[n] ? vn[n] : 0;
        idxN[n][0] = vc;
#pragma unroll
        for (int k = 1; k < KP1; ++k)
            idxN[n][k] = nbr[((size_t)b * V + vc) * 6 + (k - 1)];
    }

    f32x4 acc[4][2];
#pragma unroll
    for (int m = 0; m < 4; ++m)
#pragma unroll
        for (int n = 0; n < 2; ++n) acc[m][n] = (f32x4)0.f;

    // B-frag direct load: lane l -> row idxN[n][k_], channels c0_+seg .. +8
    auto loadB = [&](auto CHC, f16x8 (&DST)[2]) {
        constexpr int CH  = decltype(CHC)::value;
        constexpr int k_  = CH >> KSH;
        constexpr int c0_ = (CH & KMSK) * 32;
        if constexpr (INL == 0) {
            const u16* x_ = (const u16*)xin_;
#pragma unroll
            for (int n = 0; n < 2; ++n)
                DST[n] = *(const f16x8*)&x_[((size_t)b * V + idxN[n][k_]) * C + c0_ + seg];
        } else {
            const float* x_ = (const float*)xin_;
#pragma unroll
            for (int n = 0; n < 2; ++n) {
#pragma unroll
                for (int j = 0; j < 8; ++j)
                    DST[n][j] = (_Float16)x_[((size_t)b * C + c0_ + seg + j) * V + idxN[n][k_]];
            }
        }
    };

    f16x8 bf_cur[2], bf_nxt[2];
    loadB(std::integral_constant<int, 0>{}, bf_cur);

    static_for<RCH>([&](auto CHC) {
        constexpr int ch = decltype(CHC)::value;
        if constexpr (ch + 1 < RCH)
            loadB(std::integral_constant<int, ch + 1>{}, bf_nxt);
        f16x8 af[4];
#pragma unroll
        for (int m = 0; m < 4; ++m)
            af[m] = *(const f16x8*)&wF[(((size_t)ch * 8 + (wo >> 4) + m) * 64 + l) * 8];
#pragma unroll
        for (int m = 0; m < 4; ++m)
#pragma unroll
            for (int n = 0; n < 2; ++n)
                acc[m][n] = __builtin_amdgcn_mfma_f32_16x16x32_f16(af[m], bf_cur[n],
                                                                   acc[m][n], 0, 0, 0);
        if constexpr (ch + 1 < RCH) {
            bf_cur[0] = bf_nxt[0];
            bf_cur[1] = bf_nxt[1];
        }
    });

    // D layout: o = wo + m*16 + (l>>4)*4 + q ; v = vn[n]
    if constexpr (OUTL == 0) {
        u16* po = (u16*)out_;
#pragma unroll
        for (int n = 0; n < 2; ++n) {
            if (ok[n]) {
#pragma unroll
                for (int m = 0; m < 4; ++m) {
                    const int o = wo + m * 16 + ((l >> 4) << 2);
                    u16x4 pk;
#pragma unroll
                    for (int q = 0; q < 4; ++q) pk[q] = f2h(acc[m][n][q] + bias[o + q]);
                    *(u16x4*)&po[((size_t)b * V + vn[n]) * COUT + o] = pk;
                }
            }
        }
    } else {
        float* po = (float*)out_;
#pragma unroll
        for (int m = 0; m < 4; ++m) {
            const int o = wo + m * 16 + ((l >> 4) << 2);
#pragma unroll
            for (int q = 0; q < 4; ++q) {
                const float bq = bias[o + q];
#pragma unroll
                for (int n = 0; n < 2; ++n)
                    if (ok[n]) po[((size_t)(b * COUT + o + q)) * V + vn[n]] = acc[m][n][q] + bq;
            }
        }
    }

    if constexpr (STATS) {
        // per-wave partial stats of y = acc+bias over its 32 v (masked)
#pragma unroll
        for (int m = 0; m < 4; ++m) {
            const int o = wo + m * 16 + ((l >> 4) << 2);
            float s[4], s2[4];
#pragma unroll
            for (int q = 0; q < 4; ++q) {
                const float bq = bias[o + q];
                float a = 0.f, aa = 0.f;
#pragma unroll
                for (int n = 0; n < 2; ++n) {
                    if (ok[n]) {
                        const float val = acc[m][n][q] + bq;
                        a += val; aa += val * val;
                    }
                }
                s[q] = a; s2[q] = aa;
            }
#pragma unroll
            for (int d = 1; d < 16; d <<= 1) {
#pragma unroll
                for (int q = 0; q < 4; ++q) {
                    s[q]  += __shfl_xor(s[q],  d, 16);
                    s2[q] += __shfl_xor(s2[q], d, 16);
                }
            }
            if ((l & 15) == 0) {
#pragma unroll
                for (int q = 0; q < 4; ++q)
                    Sred[w][m * 16 + ((l >> 4) << 2) + q] = make_float2(s[q], s2[q]);
            }
        }
        __syncthreads();
        if (t < 128) {
            const float2 a = Sred[t >> 6][t & 63];       // wv = 0 wave
            const float2 c = Sred[(t >> 6) + 2][t & 63]; // wv = 32 wave
            P[((size_t)b * COUT + t) * NTP + tile] = make_float2(a.x + c.x, a.y + c.y);
        }
    }
}

// ---- finalize fused partials: S[row] = (mean, rsqrt(var+eps)) ----
__global__ __launch_bounds__(256) void finalize_fused(const float2* __restrict__ P,
                                                      float2* __restrict__ S) {
    const int row = blockIdx.x;       // B*COUT
    float s = 0.f, s2 = 0.f;
    for (int i = threadIdx.x; i < NT; i += 256) {
        const float2 p = P[(size_t)row * NTP + i];
        s += p.x; s2 += p.y;
    }
    __shared__ float2 red[256];
    red[threadIdx.x] = make_float2(s, s2);
    __syncthreads();
    for (int w = 128; w > 0; w >>= 1) {
        if (threadIdx.x < w) {
            red[threadIdx.x].x += red[threadIdx.x + w].x;
            red[threadIdx.x].y += red[threadIdx.x + w].y;
        }
        __syncthreads();
    }
    if (threadIdx.x == 0) {
        const float m = red[0].x / V;
        const float var = red[0].y / V - m * m;
        S[row] = make_float2(m, rsqrtf(var + EPS));
    }
}

// ---- fallback stats kernels (unfused tier, proven in round 3) ----
__global__ __launch_bounds__(256) void stats1_partial(const u16* __restrict__ x,
                                                      float2* __restrict__ P) {
    const int t = threadIdx.x;
    const int s = blockIdx.x & 63;
    const int b = blockIdx.x >> 6;
    const int o = t & 127;
    const int half = t >> 7;
    float sum = 0.f, sq = 0.f;
    for (int v = 2 * s + half; v < V; v += 128) {
        const float f = h2f(x[((size_t)b * V + v) * COUT + o]);
        sum += f; sq += f * f;
    }
    __shared__ float2 red[256];
    red[t] = make_float2(sum, sq);
    __syncthreads();
    if (t < 128) {
        const float2 o2 = red[t + 128];
        P[((size_t)b * 64 + s) * COUT + o] = make_float2(sum + o2.x, sq + o2.y);
    }
}

__global__ __launch_bounds__(256) void finalize1(const float2* __restrict__ P,
                                                 float2* __restrict__ S) {
    const int id = blockIdx.x * 256 + threadIdx.x;
    if (id >= B * COUT) return;
    float sum = 0.f, sq = 0.f;
    const int b = id >> 7, o = id & 127;
    for (int s = 0; s < 64; ++s) {
        const float2 p = P[((size_t)b * 64 + s) * COUT + o];
        sum += p.x; sq += p.y;
    }
    const float m = sum / V;
    const float var = sq / V - m * m;
    S[id] = make_float2(m, rsqrtf(var + EPS));
}

__global__ __launch_bounds__(256) void stats_f32(const float* __restrict__ y,
                                                 float2* __restrict__ S) {
    const int row = blockIdx.x;
    const float4* p = (const float4*)(y + (size_t)row * V);
    float sum = 0.f, sq = 0.f;
    for (int i = threadIdx.x; i < V / 4; i += 256) {
        const float4 f = p[i];
        sum += f.x + f.y + f.z + f.w;
        sq  += f.x * f.x + f.y * f.y + f.z * f.z + f.w * f.w;
    }
    __shared__ float2 red[256];
    red[threadIdx.x] = make_float2(sum, sq);
    __syncthreads();
    for (int w = 128; w > 0; w >>= 1) {
        if (threadIdx.x < w) {
            red[threadIdx.x].x += red[threadIdx.x + w].x;
            red[threadIdx.x].y += red[threadIdx.x + w].y;
        }
        __syncthreads();
    }
    if (threadIdx.x == 0) {
        const float m = red[0].x / V;
        const float var = red[0].y / V - m * m;
        S[row] = make_float2(m, rsqrtf(var + EPS));
    }
}

// ---- normalize + relu in place, vertex-major f16 (ws) ----
__global__ __launch_bounds__(256) void norm1(u16* __restrict__ x,
                                             const float2* __restrict__ S) {
    const unsigned e = ((unsigned)blockIdx.x * 256u + threadIdx.x) * 8u;
    if (e >= (unsigned)B * V * COUT) return;
    const unsigned b  = e / ((unsigned)V * COUT);
    const unsigned o0 = e & 127u;
    u16x8 vv = *(u16x8*)&x[e];
#pragma unroll
    for (int j = 0; j < 8; ++j) {
        const float2 s = S[b * COUT + o0 + j];
        float f = (h2f(vv[j]) - s.x) * s.y;
        vv[j] = f2h(fmaxf(f, 0.f));
    }
    *(u16x8*)&x[e] = vv;
}

// ---- final: out = relu((y2 - m)*inv + x1) in place on channel-major f32 d_out ----
__global__ __launch_bounds__(256) void final_mix(float* __restrict__ y,
                                                 const u16* __restrict__ x1,
                                                 const float2* __restrict__ S) {
    __shared__ float tile[64][33];
    const int t  = threadIdx.x;
    const int v0 = blockIdx.x * 64;
    const int o0 = blockIdx.y * 32;
    const int b  = blockIdx.z;
    const int j  = t & 31;
    const int i0 = t >> 5;
#pragma unroll
    for (int p = 0; p < 8; ++p) {
        const int i = i0 + p * 8;
        const int v = v0 + i;
        tile[i][j] = (v < V) ? h2f(x1[((size_t)b * V + v) * COUT + o0 + j]) : 0.f;
    }
    __syncthreads();
    const int vl  = t & 63;
    const int v   = v0 + vl;
    const int oo0 = t >> 6;  // 0..3
    if (v < V) {
#pragma unroll
        for (int p = 0; p < 8; ++p) {
            const int oo = oo0 + p * 4;
            const int o  = o0 + oo;
            const size_t idx = ((size_t)b * COUT + o) * V + v;
            const float2 s = S[b * COUT + o];
            const float f = (y[idx] - s.x) * s.y + tile[vl][oo];
            y[idx] = fmaxf(f, 0.f);
        }
    }
}

extern "C" void kernel_launch(void* const* d_in, const int* in_sizes, int n_in,
                              void* d_out, int out_size, void* d_ws, size_t ws_size,
                              hipStream_t stream) {
    const float* fe  = (const float*)d_in[0];
    const int*   nbr = (const int*)d_in[1];
    const float* w1  = (const float*)d_in[2];
    const float* b1  = (const float*)d_in[3];
    const float* w2  = (const float*)d_in[4];
    const float* b2  = (const float*)d_in[5];
    float* outf = (float*)d_out;
    char*  ws   = (char*)d_ws;

    constexpr size_t wF1_b = (size_t)(KP1 * CIN  / 32) * 8 * 64 * 8 * 2;  // 112 KB
    constexpr size_t wF2_b = (size_t)(KP1 * COUT / 32) * 8 * 64 * 8 * 2;  // 224 KB
    constexpr size_t S_b   = (size_t)B * COUT * 8;
    constexpr size_t Pf_b  = (size_t)B * COUT * NTP * 8;  // fused partials, 3.2 MB
    constexpr size_t Ps_b  = (size_t)B * 64 * COUT * 8;   // fallback partials, 262 KB
    constexpr size_t x1_b  = (size_t)B * V * COUT * 2;    // 51.2 MB
    constexpr size_t feT_b = (size_t)B * V * CIN * 2;     // 25.6 MB
    const size_t wsA = wF1_b + wF2_b + 2 * S_b;

    const bool fused = (ws_size >= wsA + Pf_b + x1_b);
    const bool fb    = (ws_size >= wsA + Ps_b + x1_b);
    if (!fused && !fb) return;
    const size_t P_b = fused ? Pf_b : Ps_b;
    const bool useA = (ws_size >= wsA + P_b + x1_b + feT_b);

    size_t off = 0;
    u16*    wF1 = (u16*)(ws + off);    off += wF1_b;
    u16*    wF2 = (u16*)(ws + off);    off += wF2_b;
    float2* S1  = (float2*)(ws + off); off += S_b;
    float2* S2  = (float2*)(ws + off); off += S_b;
    float2* P   = (float2*)(ws + off); off += P_b;
    u16*    x1  = (u16*)(ws + off);    off += x1_b;
    u16*    feT = nullptr;
    if (useA) { feT = (u16*)(ws + off); off += feT_b; }

    prep_wf<CIN> <<<(KP1 * CIN  / 32) * 8 * 64 / 256, 256, 0, stream>>>(w1, wF1);
    prep_wf<COUT><<<(KP1 * COUT / 32) * 8 * 64 / 256, 256, 0, stream>>>(w2, wF2);
    if (useA) {
        dim3 gt((V + 31) / 32, CIN / 32, B);
        transpose_fe<<<gt, 256, 0, stream>>>(fe, feT);
    }

    if (fused) {
        if (useA) conv_mfma<CIN, 0, 0, 1><<<B * NT, 256, 0, stream>>>(feT, wF1, b1, nbr, x1, P);
        else      conv_mfma<CIN, 1, 0, 1><<<B * NT, 256, 0, stream>>>(fe,  wF1, b1, nbr, x1, P);
        finalize_fused<<<B * COUT, 256, 0, stream>>>(P, S1);
        norm1<<<(int)((size_t)B * V * COUT / 8 / 256), 256, 0, stream>>>(x1, S1);

        conv_mfma<COUT, 0, 1, 1><<<B * NT, 256, 0, stream>>>(x1, wF2, b2, nbr, outf, P);
        finalize_fused<<<B * COUT, 256, 0, stream>>>(P, S2);
    } else {
        if (useA) conv_mfma<CIN, 0, 0, 0><<<B * NT, 256, 0, stream>>>(feT, wF1, b1, nbr, x1, nullptr);
        else      conv_mfma<CIN, 1, 0, 0><<<B * NT, 256, 0, stream>>>(fe,  wF1, b1, nbr, x1, nullptr);
        stats1_partial<<<B * 64, 256, 0, stream>>>(x1, P);
        finalize1<<<2, 256, 0, stream>>>(P, S1);
        norm1<<<(int)((size_t)B * V * COUT / 8 / 256), 256, 0, stream>>>(x1, S1);

        conv_mfma<COUT, 0, 1, 0><<<B * NT, 256, 0, stream>>>(x1, wF2, b2, nbr, outf, nullptr);
        stats_f32<<<B * COUT, 256, 0, stream>>>(outf, S2);
    }

    dim3 gf(NT64, COUT / 32, B);
    final_mix<<<gf, 256, 0, stream>>>(outf, x1, S2);
}

// Round 6
// 331.945 us; speedup vs baseline: 3.2905x; 1.0210x over previous
//
#include <hip/hip_runtime.h>
#include <cstdint>
#include <cstddef>
#include <utility>

typedef unsigned short u16;
typedef u16 u16x8 __attribute__((ext_vector_type(8)));
typedef u16 u16x4 __attribute__((ext_vector_type(4)));
typedef _Float16 f16x8 __attribute__((ext_vector_type(8)));
typedef float f32x4 __attribute__((ext_vector_type(4)));

constexpr int B    = 4;
constexpr int CIN  = 64;
constexpr int COUT = 128;
constexpr int V    = 50000;
constexpr int KP1  = 7;
constexpr float EPS = 1e-5f;

constexpr int BN  = 128;                 // vertices per conv block (4 waves x 32v)
constexpr int NT  = (V + BN - 1) / BN;   // 391
constexpr int NTP = 392;                 // padded tile stride for P
constexpr int NT64 = (V + 63) / 64;      // 782 (final_mix tiles)

__device__ __forceinline__ u16 f2h(float f) {
    _Float16 h = (_Float16)f;
    return __builtin_bit_cast(u16, h);
}
__device__ __forceinline__ float h2f(u16 s) {
    return (float)__builtin_bit_cast(_Float16, s);
}

template<int... Is, typename F>
__device__ __forceinline__ void static_for_impl(F&& f, std::integer_sequence<int, Is...>) {
    (f(std::integral_constant<int, Is>{}), ...);
}
template<int N, typename F>
__device__ __forceinline__ void static_for(F&& f) {
    static_for_impl(f, std::make_integer_sequence<int, N>{});
}

// ---- W -> fragment-ordered fp16: wF[ch][mfrag][lane][j] = W[o][r],
//      o = mfrag*16 + (lane&15), r = ch*32 + (lane>>4)*8 + j, r = k*C+c ----
template<int C>
__global__ __launch_bounds__(256) void prep_wf(const float* __restrict__ w,
                                               u16* __restrict__ wF) {
    constexpr int RCH = KP1 * C / 32;
    const int g = blockIdx.x * 256 + threadIdx.x;
    if (g >= RCH * 8 * 64) return;
    const int l  = g & 63;
    const int m  = (g >> 6) & 7;
    const int ch = g >> 9;
    const int k  = ch / (C / 32);
    const int c0 = (ch % (C / 32)) * 32;
    const int o  = m * 16 + (l & 15);
    u16x8 out;
#pragma unroll
    for (int j = 0; j < 8; ++j) {
        const int c = c0 + (l >> 4) * 8 + j;
        out[j] = f2h(w[((size_t)o * C + c) * KP1 + k]);
    }
    *(u16x8*)&wF[(size_t)g * 8] = out;
}

// ---- fe transpose: fe[b][c][v] (f32) -> feT[b][v][c] (f16) ----
__global__ __launch_bounds__(256) void transpose_fe(const float* __restrict__ fe,
                                                    u16* __restrict__ feT) {
    __shared__ u16 tile[32][33];
    const int t  = threadIdx.x;
    const int tx = t & 31, ty = t >> 5;           // 32 x 8
    const int v0 = blockIdx.x * 32;
    const int c0 = blockIdx.y * 32;
    const int b  = blockIdx.z;
#pragma unroll
    for (int p = 0; p < 4; ++p) {
        const int c = c0 + ty + p * 8;
        const int v = v0 + tx;
        if (v < V) tile[ty + p * 8][tx] = f2h(fe[((size_t)b * CIN + c) * V + v]);
    }
    __syncthreads();
#pragma unroll
    for (int p = 0; p < 4; ++p) {
        const int v = v0 + ty + p * 8;
        const int c = c0 + tx;
        if (v < V) feT[((size_t)b * V + v) * CIN + c] = tile[tx][ty + p * 8];
    }
}

// ---- MFMA gather-conv, NO LDS / NO barriers in main loop ----
// Block = 128o x 128v; 4 waves each own 128o x 32v (no duplicate gathers).
// Explicit reg pipelining: af double-buffered (ch&1), bf depth-2 (ch%3).
// INL:  0 = vertex-major f16 [B][V][C]; 1 = channel-major f32 [B][C][V]
// OUTL: 0 = vertex-major f16 [B][V][COUT] (ws); 1 = channel-major f32 (d_out)
// STATS: write per-(b,o,tile) partial (sum, sumsq) of y=conv+bias to P
template<int C, int INL, int OUTL, int STATS>
__global__ __launch_bounds__(256, 2) void conv_mfma(const void* __restrict__ xin_,
                                                    const u16*  __restrict__ wF,
                                                    const float* __restrict__ bias,
                                                    const int*  __restrict__ nbr,
                                                    void* __restrict__ out_,
                                                    float2* __restrict__ P) {
    constexpr int RCH  = KP1 * C / 32;   // 14 or 28
    constexpr int KSH  = (C == 64) ? 1 : 2;
    constexpr int KMSK = (C / 32) - 1;
    __shared__ float2 Sred[4][COUT];

    const int t    = threadIdx.x;
    const int b    = blockIdx.x / NT;
    const int tile = blockIdx.x % NT;
    const int v0   = tile * BN;
    const int w    = t >> 6;
    const int l    = t & 63;
    const int wv   = w * 32;             // wave v-offset
    const int seg  = (l >> 4) * 8;       // channel sub-offset within 32-chunk

    // hoist all neighbor indices (static indexing only -> stays in VGPRs)
    int vn[2]; bool ok[2]; int idxN[2][KP1];
#pragma unroll
    for (int n = 0; n < 2; ++n) {
        vn[n] = v0 + wv + n * 16 + (l & 15);
        ok[n] = vn[n] < V;
        const int vc = ok[n] ? vn[n] : 0;
        idxN[n][0] = vc;
#pragma unroll
        for (int k = 1; k < KP1; ++k)
            idxN[n][k] = nbr[((size_t)b * V + vc) * 6 + (k - 1)];
    }

    f32x4 acc[8][2];
#pragma unroll
    for (int m = 0; m < 8; ++m)
#pragma unroll
        for (int n = 0; n < 2; ++n) acc[m][n] = (f32x4)0.f;

    f16x8 bf[3][2];   // gather fragments, depth-2 pipeline (index = ch % 3)
    f16x8 af[2][8];   // weight fragments, double-buffered (index = ch & 1)

    // B-frag direct load: lane l -> row idxN[n][k_], channels c0_+seg .. +8
    auto loadB = [&](auto CHC, auto SLOT) {
        constexpr int CH  = decltype(CHC)::value;
        constexpr int SL  = decltype(SLOT)::value;
        constexpr int k_  = CH >> KSH;
        constexpr int c0_ = (CH & KMSK) * 32;
        if constexpr (INL == 0) {
            const u16* x_ = (const u16*)xin_;
#pragma unroll
            for (int n = 0; n < 2; ++n)
                bf[SL][n] = *(const f16x8*)&x_[((size_t)b * V + idxN[n][k_]) * C + c0_ + seg];
        } else {
            const float* x_ = (const float*)xin_;
#pragma unroll
            for (int n = 0; n < 2; ++n) {
#pragma unroll
                for (int j = 0; j < 8; ++j)
                    bf[SL][n][j] = (_Float16)x_[((size_t)b * C + c0_ + seg + j) * V + idxN[n][k_]];
            }
        }
    };
    auto loadA = [&](auto CHC, auto SLOT) {
        constexpr int CH = decltype(CHC)::value;
        constexpr int SL = decltype(SLOT)::value;
#pragma unroll
        for (int m = 0; m < 8; ++m)
            af[SL][m] = *(const f16x8*)&wF[(((size_t)CH * 8 + m) * 64 + l) * 8];
    };

    loadB(std::integral_constant<int, 0>{}, std::integral_constant<int, 0>{});
    if constexpr (RCH > 1)
        loadB(std::integral_constant<int, 1>{}, std::integral_constant<int, 1>{});
    loadA(std::integral_constant<int, 0>{}, std::integral_constant<int, 0>{});

    static_for<RCH>([&](auto CHC) {
        constexpr int ch = decltype(CHC)::value;
        if constexpr (ch + 2 < RCH)
            loadB(std::integral_constant<int, ch + 2>{},
                  std::integral_constant<int, (ch + 2) % 3>{});
        if constexpr (ch + 1 < RCH)
            loadA(std::integral_constant<int, ch + 1>{},
                  std::integral_constant<int, (ch + 1) & 1>{});
#pragma unroll
        for (int m = 0; m < 8; ++m)
#pragma unroll
            for (int n = 0; n < 2; ++n)
                acc[m][n] = __builtin_amdgcn_mfma_f32_16x16x32_f16(af[ch & 1][m],
                                                                   bf[ch % 3][n],
                                                                   acc[m][n], 0, 0, 0);
    });

    // D layout: o = m*16 + (l>>4)*4 + q ; v = vn[n]
    if constexpr (OUTL == 0) {
        u16* po = (u16*)out_;
#pragma unroll
        for (int n = 0; n < 2; ++n) {
            if (ok[n]) {
#pragma unroll
                for (int m = 0; m < 8; ++m) {
                    const int o = m * 16 + ((l >> 4) << 2);
                    u16x4 pk;
#pragma unroll
                    for (int q = 0; q < 4; ++q) pk[q] = f2h(acc[m][n][q] + bias[o + q]);
                    *(u16x4*)&po[((size_t)b * V + vn[n]) * COUT + o] = pk;
                }
            }
        }
    } else {
        float* po = (float*)out_;
#pragma unroll
        for (int m = 0; m < 8; ++m) {
            const int o = m * 16 + ((l >> 4) << 2);
#pragma unroll
            for (int q = 0; q < 4; ++q) {
                const float bq = bias[o + q];
#pragma unroll
                for (int n = 0; n < 2; ++n)
                    if (ok[n]) po[((size_t)(b * COUT + o + q)) * V + vn[n]] = acc[m][n][q] + bq;
            }
        }
    }

    if constexpr (STATS) {
        // per-wave partial stats of y = acc+bias over its 32 v (masked)
#pragma unroll
        for (int m = 0; m < 8; ++m) {
            const int o = m * 16 + ((l >> 4) << 2);
            float s[4], s2[4];
#pragma unroll
            for (int q = 0; q < 4; ++q) {
                const float bq = bias[o + q];
                float a = 0.f, aa = 0.f;
#pragma unroll
                for (int n = 0; n < 2; ++n) {
                    if (ok[n]) {
                        const float val = acc[m][n][q] + bq;
                        a += val; aa += val * val;
                    }
                }
                s[q] = a; s2[q] = aa;
            }
#pragma unroll
            for (int d = 1; d < 16; d <<= 1) {
#pragma unroll
                for (int q = 0; q < 4; ++q) {
                    s[q]  += __shfl_xor(s[q],  d, 16);
                    s2[q] += __shfl_xor(s2[q], d, 16);
                }
            }
            if ((l & 15) == 0) {
#pragma unroll
                for (int q = 0; q < 4; ++q)
                    Sred[w][o + q] = make_float2(s[q], s2[q]);
            }
        }
        __syncthreads();
        if (t < COUT) {
            float2 r = Sred[0][t];
            const float2 r1 = Sred[1][t];
            const float2 r2 = Sred[2][t];
            const float2 r3 = Sred[3][t];
            r.x += r1.x + r2.x + r3.x;
            r.y += r1.y + r2.y + r3.y;
            P[((size_t)b * COUT + t) * NTP + tile] = r;
        }
    }
}

// ---- finalize fused partials: S[row] = (mean, rsqrt(var+eps)) ----
__global__ __launch_bounds__(256) void finalize_fused(const float2* __restrict__ P,
                                                      float2* __restrict__ S) {
    const int row = blockIdx.x;       // B*COUT
    float s = 0.f, s2 = 0.f;
    for (int i = threadIdx.x; i < NT; i += 256) {
        const float2 p = P[(size_t)row * NTP + i];
        s += p.x; s2 += p.y;
    }
    __shared__ float2 red[256];
    red[threadIdx.x] = make_float2(s, s2);
    __syncthreads();
    for (int w = 128; w > 0; w >>= 1) {
        if (threadIdx.x < w) {
            red[threadIdx.x].x += red[threadIdx.x + w].x;
            red[threadIdx.x].y += red[threadIdx.x + w].y;
        }
        __syncthreads();
    }
    if (threadIdx.x == 0) {
        const float m = red[0].x / V;
        const float var = red[0].y / V - m * m;
        S[row] = make_float2(m, rsqrtf(var + EPS));
    }
}

// ---- fallback stats kernels (unfused tier) ----
__global__ __launch_bounds__(256) void stats1_partial(const u16* __restrict__ x,
                                                      float2* __restrict__ P) {
    const int t = threadIdx.x;
    const int s = blockIdx.x & 63;
    const int b = blockIdx.x >> 6;
    const int o = t & 127;
    const int half = t >> 7;
    float sum = 0.f, sq = 0.f;
    for (int v = 2 * s + half; v < V; v += 128) {
        const float f = h2f(x[((size_t)b * V + v) * COUT + o]);
        sum += f; sq += f * f;
    }
    __shared__ float2 red[256];
    red[t] = make_float2(sum, sq);
    __syncthreads();
    if (t < 128) {
        const float2 o2 = red[t + 128];
        P[((size_t)b * 64 + s) * COUT + o] = make_float2(sum + o2.x, sq + o2.y);
    }
}

__global__ __launch_bounds__(256) void finalize1(const float2* __restrict__ P,
                                                 float2* __restrict__ S) {
    const int id = blockIdx.x * 256 + threadIdx.x;
    if (id >= B * COUT) return;
    float sum = 0.f, sq = 0.f;
    const int b = id >> 7, o = id & 127;
    for (int s = 0; s < 64; ++s) {
        const float2 p = P[((size_t)b * 64 + s) * COUT + o];
        sum += p.x; sq += p.y;
    }
    const float m = sum / V;
    const float var = sq / V - m * m;
    S[id] = make_float2(m, rsqrtf(var + EPS));
}

__global__ __launch_bounds__(256) void stats_f32(const float* __restrict__ y,
                                                 float2* __restrict__ S) {
    const int row = blockIdx.x;
    const float4* p = (const float4*)(y + (size_t)row * V);
    float sum = 0.f, sq = 0.f;
    for (int i = threadIdx.x; i < V / 4; i += 256) {
        const float4 f = p[i];
        sum += f.x + f.y + f.z + f.w;
        sq  += f.x * f.x + f.y * f.y + f.z * f.z + f.w * f.w;
    }
    __shared__ float2 red[256];
    red[threadIdx.x] = make_float2(sum, sq);
    __syncthreads();
    for (int w = 128; w > 0; w >>= 1) {
        if (threadIdx.x < w) {
            red[threadIdx.x].x += red[threadIdx.x + w].x;
            red[threadIdx.x].y += red[threadIdx.x + w].y;
        }
        __syncthreads();
    }
    if (threadIdx.x == 0) {
        const float m = red[0].x / V;
        const float var = red[0].y / V - m * m;
        S[row] = make_float2(m, rsqrtf(var + EPS));
    }
}

// ---- normalize + relu in place, vertex-major f16 (ws) ----
__global__ __launch_bounds__(256) void norm1(u16* __restrict__ x,
                                             const float2* __restrict__ S) {
    const unsigned e = ((unsigned)blockIdx.x * 256u + threadIdx.x) * 8u;
    if (e >= (unsigned)B * V * COUT) return;
    const unsigned b  = e / ((unsigned)V * COUT);
    const unsigned o0 = e & 127u;
    u16x8 vv = *(u16x8*)&x[e];
#pragma unroll
    for (int j = 0; j < 8; ++j) {
        const float2 s = S[b * COUT + o0 + j];
        float f = (h2f(vv[j]) - s.x) * s.y;
        vv[j] = f2h(fmaxf(f, 0.f));
    }
    *(u16x8*)&x[e] = vv;
}

// ---- final: out = relu((y2 - m)*inv + x1) in place on channel-major f32 d_out ----
__global__ __launch_bounds__(256) void final_mix(float* __restrict__ y,
                                                 const u16* __restrict__ x1,
                                                 const float2* __restrict__ S) {
    __shared__ float tile[64][33];
    const int t  = threadIdx.x;
    const int v0 = blockIdx.x * 64;
    const int o0 = blockIdx.y * 32;
    const int b  = blockIdx.z;
    const int j  = t & 31;
    const int i0 = t >> 5;
#pragma unroll
    for (int p = 0; p < 8; ++p) {
        const int i = i0 + p * 8;
        const int v = v0 + i;
        tile[i][j] = (v < V) ? h2f(x1[((size_t)b * V + v) * COUT + o0 + j]) : 0.f;
    }
    __syncthreads();
    const int vl  = t & 63;
    const int v   = v0 + vl;
    const int oo0 = t >> 6;  // 0..3
    if (v < V) {
#pragma unroll
        for (int p = 0; p < 8; ++p) {
            const int oo = oo0 + p * 4;
            const int o  = o0 + oo;
            const size_t idx = ((size_t)b * COUT + o) * V + v;
            const float2 s = S[b * COUT + o];
            const float f = (y[idx] - s.x) * s.y + tile[vl][oo];
            y[idx] = fmaxf(f, 0.f);
        }
    }
}

extern "C" void kernel_launch(void* const* d_in, const int* in_sizes, int n_in,
                              void* d_out, int out_size, void* d_ws, size_t ws_size,
                              hipStream_t stream) {
    const float* fe  = (const float*)d_in[0];
    const int*   nbr = (const int*)d_in[1];
    const float* w1  = (const float*)d_in[2];
    const float* b1  = (const float*)d_in[3];
    const float* w2  = (const float*)d_in[4];
    const float* b2  = (const float*)d_in[5];
    float* outf = (float*)d_out;
    char*  ws   = (char*)d_ws;

    constexpr size_t wF1_b = (size_t)(KP1 * CIN  / 32) * 8 * 64 * 8 * 2;  // 112 KB
    constexpr size_t wF2_b = (size_t)(KP1 * COUT / 32) * 8 * 64 * 8 * 2;  // 224 KB
    constexpr size_t S_b   = (size_t)B * COUT * 8;
    constexpr size_t Pf_b  = (size_t)B * COUT * NTP * 8;  // fused partials, 1.6 MB
    constexpr size_t Ps_b  = (size_t)B * 64 * COUT * 8;   // fallback partials, 262 KB
    constexpr size_t x1_b  = (size_t)B * V * COUT * 2;    // 51.2 MB
    constexpr size_t feT_b = (size_t)B * V * CIN * 2;     // 25.6 MB
    const size_t wsA = wF1_b + wF2_b + 2 * S_b;

    const bool fused = (ws_size >= wsA + Pf_b + x1_b);
    const bool fb    = (ws_size >= wsA + Ps_b + x1_b);
    if (!fused && !fb) return;
    const size_t P_b = fused ? Pf_b : Ps_b;
    const bool useA = (ws_size >= wsA + P_b + x1_b + feT_b);

    size_t off = 0;
    u16*    wF1 = (u16*)(ws + off);    off += wF1_b;
    u16*    wF2 = (u16*)(ws + off);    off += wF2_b;
    float2* S1  = (float2*)(ws + off); off += S_b;
    float2* S2  = (float2*)(ws + off); off += S_b;
    float2* P   = (float2*)(ws + off); off += P_b;
    u16*    x1  = (u16*)(ws + off);    off += x1_b;
    u16*    feT = nullptr;
    if (useA) { feT = (u16*)(ws + off); off += feT_b; }

    prep_wf<CIN> <<<(KP1 * CIN  / 32) * 8 * 64 / 256, 256, 0, stream>>>(w1, wF1);
    prep_wf<COUT><<<(KP1 * COUT / 32) * 8 * 64 / 256, 256, 0, stream>>>(w2, wF2);
    if (useA) {
        dim3 gt((V + 31) / 32, CIN / 32, B);
        transpose_fe<<<gt, 256, 0, stream>>>(fe, feT);
    }

    if (fused) {
        if (useA) conv_mfma<CIN, 0, 0, 1><<<B * NT, 256, 0, stream>>>(feT, wF1, b1, nbr, x1, P);
        else      conv_mfma<CIN, 1, 0, 1><<<B * NT, 256, 0, stream>>>(fe,  wF1, b1, nbr, x1, P);
        finalize_fused<<<B * COUT, 256, 0, stream>>>(P, S1);
        norm1<<<(int)((size_t)B * V * COUT / 8 / 256), 256, 0, stream>>>(x1, S1);

        conv_mfma<COUT, 0, 1, 1><<<B * NT, 256, 0, stream>>>(x1, wF2, b2, nbr, outf, P);
        finalize_fused<<<B * COUT, 256, 0, stream>>>(P, S2);
    } else {
        if (useA) conv_mfma<CIN, 0, 0, 0><<<B * NT, 256, 0, stream>>>(feT, wF1, b1, nbr, x1, nullptr);
        else      conv_mfma<CIN, 1, 0, 0><<<B * NT, 256, 0, stream>>>(fe,  wF1, b1, nbr, x1, nullptr);
        stats1_partial<<<B * 64, 256, 0, stream>>>(x1, P);
        finalize1<<<2, 256, 0, stream>>>(P, S1);
        norm1<<<(int)((size_t)B * V * COUT / 8 / 256), 256, 0, stream>>>(x1, S1);

        conv_mfma<COUT, 0, 1, 0><<<B * NT, 256, 0, stream>>>(x1, wF2, b2, nbr, outf, nullptr);
        stats_f32<<<B * COUT, 256, 0, stream>>>(outf, S2);
    }

    dim3 gf(NT64, COUT / 32, B);
    final_mix<<<gf, 256, 0, stream>>>(outf, x1, S2);
}

// Round 7
// 236.509 us; speedup vs baseline: 4.6182x; 1.4035x over previous
//
#include <hip/hip_runtime.h>
#include <cstdint>
#include <cstddef>
#include <utility>

typedef unsigned short u16;
typedef u16 u16x8 __attribute__((ext_vector_type(8)));
typedef u16 u16x4 __attribute__((ext_vector_type(4)));
typedef _Float16 f16x8 __attribute__((ext_vector_type(8)));
typedef float f32x4 __attribute__((ext_vector_type(4)));

constexpr int B    = 4;
constexpr int CIN  = 64;
constexpr int COUT = 128;
constexpr int V    = 50000;
constexpr int KP1  = 7;
constexpr float EPS = 1e-5f;

constexpr int BN   = 128;                // vertices per conv block
constexpr int NT   = (V + BN - 1) / BN;  // 391
constexpr int NTP  = 392;                // padded tile stride for P
constexpr int NT64 = (V + 63) / 64;      // 782 (final_mix tiles)

__device__ __forceinline__ u16 f2h(float f) {
    _Float16 h = (_Float16)f;
    return __builtin_bit_cast(u16, h);
}
__device__ __forceinline__ float h2f(u16 s) {
    return (float)__builtin_bit_cast(_Float16, s);
}

template<int... Is, typename F>
__device__ __forceinline__ void static_for_impl(F&& f, std::integer_sequence<int, Is...>) {
    (f(std::integral_constant<int, Is>{}), ...);
}
template<int N, typename F>
__device__ __forceinline__ void static_for(F&& f) {
    static_for_impl(f, std::make_integer_sequence<int, N>{});
}

// ---- W -> fragment-ordered fp16: wF[ch][mfrag][lane][j] = W[o][r],
//      o = mfrag*16 + (lane&15), r = ch*32 + (lane>>4)*8 + j, r = k*C+c ----
template<int C>
__global__ __launch_bounds__(256) void prep_wf(const float* __restrict__ w,
                                               u16* __restrict__ wF) {
    constexpr int RCH = KP1 * C / 32;
    const int g = blockIdx.x * 256 + threadIdx.x;
    if (g >= RCH * 8 * 64) return;
    const int l  = g & 63;
    const int m  = (g >> 6) & 7;
    const int ch = g >> 9;
    const int k  = ch / (C / 32);
    const int c0 = (ch % (C / 32)) * 32;
    const int o  = m * 16 + (l & 15);
    u16x8 out;
#pragma unroll
    for (int j = 0; j < 8; ++j) {
        const int c = c0 + (l >> 4) * 8 + j;
        out[j] = f2h(w[((size_t)o * C + c) * KP1 + k]);
    }
    *(u16x8*)&wF[(size_t)g * 8] = out;
}

// ---- fe transpose: fe[b][c][v] (f32) -> feT[b][v][c] (f16) ----
__global__ __launch_bounds__(256) void transpose_fe(const float* __restrict__ fe,
                                                    u16* __restrict__ feT) {
    __shared__ u16 tile[32][33];
    const int t  = threadIdx.x;
    const int tx = t & 31, ty = t >> 5;           // 32 x 8
    const int v0 = blockIdx.x * 32;
    const int c0 = blockIdx.y * 32;
    const int b  = blockIdx.z;
#pragma unroll
    for (int p = 0; p < 4; ++p) {
        const int c = c0 + ty + p * 8;
        const int v = v0 + tx;
        if (v < V) tile[ty + p * 8][tx] = f2h(fe[((size_t)b * CIN + c) * V + v]);
    }
    __syncthreads();
#pragma unroll
    for (int p = 0; p < 4; ++p) {
        const int v = v0 + ty + p * 8;
        const int c = c0 + tx;
        if (v < V) feT[((size_t)b * V + v) * CIN + c] = tile[tx][ty + p * 8];
    }
}

// ---- MFMA gather-conv: LDS-staged X, 3-buffer depth-2 pipeline, raw barriers.
// Block = 128o x 128v; waves 2x2, wave tile 64o x 64v.
// INL:  0 = vertex-major f16 [B][V][C]; 1 = channel-major f32 [B][C][V]
// OUTL: 0 = vertex-major f16 [B][V][COUT] (ws); 1 = channel-major f32 (d_out)
// Always fuses instance-norm partial stats (sum, sumsq) into P.
template<int C, int INL, int OUTL>
__global__ __launch_bounds__(256, 3) void conv_mfma(const void* __restrict__ xin_,
                                                    const u16*  __restrict__ wF,
                                                    const float* __restrict__ bias,
                                                    const int*  __restrict__ nbr,
                                                    void* __restrict__ out_,
                                                    float2* __restrict__ P) {
    constexpr int RCH  = KP1 * C / 32;   // 14 or 28
    constexpr int KSH  = (C == 64) ? 1 : 2;
    constexpr int KMSK = (C / 32) - 1;
    __shared__ __align__(16) u16 Xl[3][BN][40];   // 30.7 KB, rows 80B (16B-aligned)
    __shared__ float2 Sred[4][COUT];

    const int t    = threadIdx.x;
    const int b    = blockIdx.x / NT;
    const int tile = blockIdx.x % NT;
    const int v0   = tile * BN;
    const int w    = t >> 6;
    const int l    = t & 63;
    const int wo   = (w & 1) * 64;       // wave o-offset
    const int wv   = (w >> 1) * 64;      // wave v-offset
    const int seg  = (l >> 4) * 8;       // u16 offset within 32-chunk

    // staging role: row sv = t>>1 (0..127), channel half hc = (t&1)*16
    const int sv = t >> 1;
    const int hc = (t & 1) * 16;
    const int vS = v0 + sv;
    const bool okS = vS < V;
    int idxS[KP1];
    {
        const int vc = okS ? vS : 0;
        idxS[0] = vc;
#pragma unroll
        for (int k = 1; k < KP1; ++k)
            idxS[k] = nbr[((size_t)b * V + vc) * 6 + (k - 1)];
    }

    // consumer vertices
    int vn[4]; bool ok[4];
#pragma unroll
    for (int n = 0; n < 4; ++n) {
        vn[n] = v0 + wv + n * 16 + (l & 15);
        ok[n] = vn[n] < V;
    }

    f32x4 acc[4][4];
#pragma unroll
    for (int m = 0; m < 4; ++m)
#pragma unroll
        for (int n = 0; n < 4; ++n) acc[m][n] = (f32x4)0.f;

    f16x8 af[2][4];   // weight frags, double-buffered
    u16x8 g[2][2];    // gather regs, 2 sets (depth-2)

    auto gload = [&](auto CHC, u16x8 (&gr)[2]) {
        constexpr int CH  = decltype(CHC)::value;
        constexpr int k_  = CH >> KSH;
        constexpr int c0_ = (CH & KMSK) * 32;
        if constexpr (INL == 0) {
            const u16* x_ = (const u16*)xin_;
            const u16* p_ = &x_[((size_t)b * V + idxS[k_]) * C + c0_ + hc];
            gr[0] = *(const u16x8*)(p_);
            gr[1] = *(const u16x8*)(p_ + 8);
        } else {
            const float* x_ = (const float*)xin_;
#pragma unroll
            for (int j = 0; j < 16; ++j) {
                const float v_ = x_[((size_t)b * C + c0_ + hc + j) * V + idxS[k_]];
                gr[j >> 3][j & 7] = f2h(v_);
            }
        }
    };
    auto aload = [&](auto CHC, f16x8 (&ar)[4]) {
        constexpr int CH = decltype(CHC)::value;
#pragma unroll
        for (int m = 0; m < 4; ++m)
            ar[m] = *(const f16x8*)&wF[(((size_t)CH * 8 + (wo >> 4) + m) * 64 + l) * 8];
    };

    // prologue: chunk0 -> buf0 via g[0]; chunk1 -> g[1]; af(0)
    gload(std::integral_constant<int, 0>{}, g[0]);
    gload(std::integral_constant<int, 1>{}, g[1]);
    aload(std::integral_constant<int, 0>{}, af[0]);
    *(u16x8*)&Xl[0][sv][hc]     = g[0][0];
    *(u16x8*)&Xl[0][sv][hc + 8] = g[0][1];
    asm volatile("s_waitcnt lgkmcnt(0)" ::: "memory");
    __builtin_amdgcn_s_barrier();

    static_for<RCH>([&](auto CHC) {
        constexpr int ch = decltype(CHC)::value;
        constexpr int rb = ch % 3;
        f16x8 bf[4];
#pragma unroll
        for (int n = 0; n < 4; ++n)
            bf[n] = *(const f16x8*)&Xl[rb][wv + n * 16 + (l & 15)][seg];
        if constexpr (ch + 1 < RCH) {
            aload(std::integral_constant<int, ch + 1>{}, af[(ch + 1) & 1]);
            constexpr int wb = (ch + 1) % 3;
            // chunk ch+1 data was issued at iter ch-1 (or prologue) into g[(ch+1)&1]
            *(u16x8*)&Xl[wb][sv][hc]     = g[(ch + 1) & 1][0];
            *(u16x8*)&Xl[wb][sv][hc + 8] = g[(ch + 1) & 1][1];
        }
        if constexpr (ch + 2 < RCH)
            gload(std::integral_constant<int, ch + 2>{}, g[ch & 1]);
#pragma unroll
        for (int m = 0; m < 4; ++m)
#pragma unroll
            for (int n = 0; n < 4; ++n)
                acc[m][n] = __builtin_amdgcn_mfma_f32_16x16x32_f16(af[ch & 1][m], bf[n],
                                                                   acc[m][n], 0, 0, 0);
        if constexpr (ch + 1 < RCH) {
            asm volatile("s_waitcnt lgkmcnt(0)" ::: "memory");
            __builtin_amdgcn_s_barrier();
        }
    });

    // D layout: o = wo + m*16 + (l>>4)*4 + q ; v = vn[n]
    if constexpr (OUTL == 0) {
        u16* po = (u16*)out_;
#pragma unroll
        for (int n = 0; n < 4; ++n) {
            if (ok[n]) {
#pragma unroll
                for (int m = 0; m < 4; ++m) {
                    const int o = wo + m * 16 + ((l >> 4) << 2);
                    u16x4 pk;
#pragma unroll
                    for (int q = 0; q < 4; ++q) pk[q] = f2h(acc[m][n][q] + bias[o + q]);
                    *(u16x4*)&po[((size_t)b * V + vn[n]) * COUT + o] = pk;
                }
            }
        }
    } else {
        float* po = (float*)out_;
#pragma unroll
        for (int m = 0; m < 4; ++m) {
            const int o = wo + m * 16 + ((l >> 4) << 2);
#pragma unroll
            for (int q = 0; q < 4; ++q) {
                const float bq = bias[o + q];
#pragma unroll
                for (int n = 0; n < 4; ++n)
                    if (ok[n]) po[((size_t)(b * COUT + o + q)) * V + vn[n]] = acc[m][n][q] + bq;
            }
        }
    }

    // fused instance-norm partials
#pragma unroll
    for (int m = 0; m < 4; ++m) {
        const int o = wo + m * 16 + ((l >> 4) << 2);
        float s[4], s2[4];
#pragma unroll
        for (int q = 0; q < 4; ++q) {
            const float bq = bias[o + q];
            float a = 0.f, aa = 0.f;
#pragma unroll
            for (int n = 0; n < 4; ++n) {
                if (ok[n]) {
                    const float val = acc[m][n][q] + bq;
                    a += val; aa += val * val;
                }
            }
            s[q] = a; s2[q] = aa;
        }
#pragma unroll
        for (int d = 1; d < 16; d <<= 1) {
#pragma unroll
            for (int q = 0; q < 4; ++q) {
                s[q]  += __shfl_xor(s[q],  d, 16);
                s2[q] += __shfl_xor(s2[q], d, 16);
            }
        }
        if ((l & 15) == 0) {
#pragma unroll
            for (int q = 0; q < 4; ++q)
                Sred[w][o + q] = make_float2(s[q], s2[q]);
        }
    }
    __syncthreads();
    if (t < COUT) {
        const int wlo = t >> 6;            // o-half -> waves wlo and wlo+2
        const float2 a = Sred[wlo][t];
        const float2 c = Sred[wlo + 2][t];
        P[((size_t)b * COUT + t) * NTP + tile] = make_float2(a.x + c.x, a.y + c.y);
    }
}

// ---- finalize fused partials: S[row] = (mean, rsqrt(var+eps)) ----
__global__ __launch_bounds__(256) void finalize_fused(const float2* __restrict__ P,
                                                      float2* __restrict__ S) {
    const int row = blockIdx.x;       // B*COUT
    float s = 0.f, s2 = 0.f;
    for (int i = threadIdx.x; i < NT; i += 256) {
        const float2 p = P[(size_t)row * NTP + i];
        s += p.x; s2 += p.y;
    }
    __shared__ float2 red[256];
    red[threadIdx.x] = make_float2(s, s2);
    __syncthreads();
    for (int w = 128; w > 0; w >>= 1) {
        if (threadIdx.x < w) {
            red[threadIdx.x].x += red[threadIdx.x + w].x;
            red[threadIdx.x].y += red[threadIdx.x + w].y;
        }
        __syncthreads();
    }
    if (threadIdx.x == 0) {
        const float m = red[0].x / V;
        const float var = red[0].y / V - m * m;
        S[row] = make_float2(m, rsqrtf(var + EPS));
    }
}

// ---- normalize + relu in place, vertex-major f16 (ws) ----
__global__ __launch_bounds__(256) void norm1(u16* __restrict__ x,
                                             const float2* __restrict__ S) {
    const unsigned e = ((unsigned)blockIdx.x * 256u + threadIdx.x) * 8u;
    if (e >= (unsigned)B * V * COUT) return;
    const unsigned b  = e / ((unsigned)V * COUT);
    const unsigned o0 = e & 127u;
    u16x8 vv = *(u16x8*)&x[e];
#pragma unroll
    for (int j = 0; j < 8; ++j) {
        const float2 s = S[b * COUT + o0 + j];
        float f = (h2f(vv[j]) - s.x) * s.y;
        vv[j] = f2h(fmaxf(f, 0.f));
    }
    *(u16x8*)&x[e] = vv;
}

// ---- final (full tier): y2,x1 vertex-major f16 -> out channel-major f32 ----
__global__ __launch_bounds__(256) void final_mix2(const u16* __restrict__ y2,
                                                  const u16* __restrict__ x1,
                                                  const float2* __restrict__ S,
                                                  float* __restrict__ out) {
    __shared__ float ty[64][33], tx[64][33];
    const int t  = threadIdx.x;
    const int v0 = blockIdx.x * 64;
    const int o0 = blockIdx.y * 32;
    const int b  = blockIdx.z;
    const int jr = (t & 7) * 4;
    const int ir = t >> 3;             // 0..31
#pragma unroll
    for (int p = 0; p < 2; ++p) {
        const int i = ir + p * 32;
        const int v = v0 + i;
        if (v < V) {
            const size_t base = ((size_t)b * V + v) * COUT + o0 + jr;
            const u16x4 a = *(const u16x4*)&y2[base];
            const u16x4 c = *(const u16x4*)&x1[base];
#pragma unroll
            for (int q = 0; q < 4; ++q) {
                ty[i][jr + q] = h2f(a[q]);
                tx[i][jr + q] = h2f(c[q]);
            }
        }
    }
    __syncthreads();
    const int vl = t & 63, v = v0 + vl, oo0 = t >> 6;
    if (v < V) {
#pragma unroll
        for (int p = 0; p < 8; ++p) {
            const int oo = oo0 + p * 4;
            const int o  = o0 + oo;
            const float2 s = S[b * COUT + o];
            out[((size_t)b * COUT + o) * V + v] =
                fmaxf((ty[vl][oo] - s.x) * s.y + tx[vl][oo], 0.f);
        }
    }
}

// ---- final (fallback tier): y f32 CM in place; x1 f16 VM staged via LDS ----
__global__ __launch_bounds__(256) void final_mix(float* __restrict__ y,
                                                 const u16* __restrict__ x1,
                                                 const float2* __restrict__ S) {
    __shared__ float tile[64][33];
    const int t  = threadIdx.x;
    const int v0 = blockIdx.x * 64;
    const int o0 = blockIdx.y * 32;
    const int b  = blockIdx.z;
    const int j  = t & 31;
    const int i0 = t >> 5;
#pragma unroll
    for (int p = 0; p < 8; ++p) {
        const int i = i0 + p * 8;
        const int v = v0 + i;
        tile[i][j] = (v < V) ? h2f(x1[((size_t)b * V + v) * COUT + o0 + j]) : 0.f;
    }
    __syncthreads();
    const int vl  = t & 63;
    const int v   = v0 + vl;
    const int oo0 = t >> 6;
    if (v < V) {
#pragma unroll
        for (int p = 0; p < 8; ++p) {
            const int oo = oo0 + p * 4;
            const int o  = o0 + oo;
            const size_t idx = ((size_t)b * COUT + o) * V + v;
            const float2 s = S[b * COUT + o];
            const float f = (y[idx] - s.x) * s.y + tile[vl][oo];
            y[idx] = fmaxf(f, 0.f);
        }
    }
}

extern "C" void kernel_launch(void* const* d_in, const int* in_sizes, int n_in,
                              void* d_out, int out_size, void* d_ws, size_t ws_size,
                              hipStream_t stream) {
    const float* fe  = (const float*)d_in[0];
    const int*   nbr = (const int*)d_in[1];
    const float* w1  = (const float*)d_in[2];
    const float* b1  = (const float*)d_in[3];
    const float* w2  = (const float*)d_in[4];
    const float* b2  = (const float*)d_in[5];
    float* outf = (float*)d_out;
    char*  ws   = (char*)d_ws;

    constexpr size_t wF1_b = (size_t)(KP1 * CIN  / 32) * 8 * 64 * 8 * 2;  // 112 KB
    constexpr size_t wF2_b = (size_t)(KP1 * COUT / 32) * 8 * 64 * 8 * 2;  // 224 KB
    constexpr size_t S_b   = (size_t)B * COUT * 8;
    constexpr size_t Pf_b  = (size_t)B * COUT * NTP * 8;  // 1.6 MB
    constexpr size_t x1_b  = (size_t)B * V * COUT * 2;    // 51.2 MB
    constexpr size_t y2_b  = (size_t)B * V * COUT * 2;    // 51.2 MB
    constexpr size_t feT_b = (size_t)B * V * CIN * 2;     // 25.6 MB
    const size_t base = wF1_b + wF2_b + 2 * S_b + Pf_b;

    // tiers: full (y2 overlays feT region), T3 (feT, f32-CM out), T4 (minimal)
    const bool full = (ws_size >= base + x1_b + y2_b);    // ~104.4 MB
    const bool t3   = (ws_size >= base + x1_b + feT_b);   // ~78.8 MB
    const bool t4   = (ws_size >= base + x1_b);           // ~53.2 MB
    if (!full && !t3 && !t4) return;

    size_t off = 0;
    u16*    wF1 = (u16*)(ws + off);    off += wF1_b;
    u16*    wF2 = (u16*)(ws + off);    off += wF2_b;
    float2* S1  = (float2*)(ws + off); off += S_b;
    float2* S2  = (float2*)(ws + off); off += S_b;
    float2* P   = (float2*)(ws + off); off += Pf_b;
    u16*    x1  = (u16*)(ws + off);    off += x1_b;
    u16*    ext = (u16*)(ws + off);    // feT and/or y2 region

    prep_wf<CIN> <<<(KP1 * CIN  / 32) * 8 * 64 / 256, 256, 0, stream>>>(w1, wF1);
    prep_wf<COUT><<<(KP1 * COUT / 32) * 8 * 64 / 256, 256, 0, stream>>>(w2, wF2);

    const bool useFeT = full || t3;
    if (useFeT) {
        dim3 gt((V + 31) / 32, CIN / 32, B);
        transpose_fe<<<gt, 256, 0, stream>>>(fe, ext);   // feT at ext
    }

    if (useFeT) conv_mfma<CIN, 0, 0><<<B * NT, 256, 0, stream>>>(ext, wF1, b1, nbr, x1, P);
    else        conv_mfma<CIN, 1, 0><<<B * NT, 256, 0, stream>>>(fe,  wF1, b1, nbr, x1, P);
    finalize_fused<<<B * COUT, 256, 0, stream>>>(P, S1);
    norm1<<<(int)((size_t)B * V * COUT / 8 / 256), 256, 0, stream>>>(x1, S1);

    dim3 gf(NT64, COUT / 32, B);
    if (full) {
        u16* y2 = ext;   // overlays feT (dead after conv1)
        conv_mfma<COUT, 0, 0><<<B * NT, 256, 0, stream>>>(x1, wF2, b2, nbr, y2, P);
        finalize_fused<<<B * COUT, 256, 0, stream>>>(P, S2);
        final_mix2<<<gf, 256, 0, stream>>>(y2, x1, S2, outf);
    } else {
        conv_mfma<COUT, 0, 1><<<B * NT, 256, 0, stream>>>(x1, wF2, b2, nbr, outf, P);
        finalize_fused<<<B * COUT, 256, 0, stream>>>(P, S2);
        final_mix<<<gf, 256, 0, stream>>>(outf, x1, S2);
    }
}

// Round 8
// 233.407 us; speedup vs baseline: 4.6796x; 1.0133x over previous
//
#include <hip/hip_runtime.h>
#include <cstdint>
#include <cstddef>
#include <utility>

typedef unsigned short u16;
typedef u16 u16x8 __attribute__((ext_vector_type(8)));
typedef u16 u16x4 __attribute__((ext_vector_type(4)));
typedef _Float16 f16x8 __attribute__((ext_vector_type(8)));
typedef float f32x4 __attribute__((ext_vector_type(4)));

constexpr int B    = 4;
constexpr int CIN  = 64;
constexpr int COUT = 128;
constexpr int V    = 50000;
constexpr int KP1  = 7;
constexpr float EPS = 1e-5f;

constexpr int BN   = 128;                // vertices per conv block
constexpr int NT   = (V + BN - 1) / BN;  // 391
constexpr int NTP  = 392;                // padded tile stride for P
constexpr int NT64 = (V + 63) / 64;      // 782 (final_mix tiles)

__device__ __forceinline__ u16 f2h(float f) {
    _Float16 h = (_Float16)f;
    return __builtin_bit_cast(u16, h);
}
__device__ __forceinline__ float h2f(u16 s) {
    return (float)__builtin_bit_cast(_Float16, s);
}

template<int... Is, typename F>
__device__ __forceinline__ void static_for_impl(F&& f, std::integer_sequence<int, Is...>) {
    (f(std::integral_constant<int, Is>{}), ...);
}
template<int N, typename F>
__device__ __forceinline__ void static_for(F&& f) {
    static_for_impl(f, std::make_integer_sequence<int, N>{});
}

// ---- W -> fragment-ordered fp16: wF[ch][mfrag][lane][j] = W[o][r],
//      o = mfrag*16 + (lane&15), r = ch*32 + (lane>>4)*8 + j, r = k*C+c ----
template<int C>
__global__ __launch_bounds__(256) void prep_wf(const float* __restrict__ w,
                                               u16* __restrict__ wF) {
    constexpr int RCH = KP1 * C / 32;
    const int g = blockIdx.x * 256 + threadIdx.x;
    if (g >= RCH * 8 * 64) return;
    const int l  = g & 63;
    const int m  = (g >> 6) & 7;
    const int ch = g >> 9;
    const int k  = ch / (C / 32);
    const int c0 = (ch % (C / 32)) * 32;
    const int o  = m * 16 + (l & 15);
    u16x8 out;
#pragma unroll
    for (int j = 0; j < 8; ++j) {
        const int c = c0 + (l >> 4) * 8 + j;
        out[j] = f2h(w[((size_t)o * C + c) * KP1 + k]);
    }
    *(u16x8*)&wF[(size_t)g * 8] = out;
}

// ---- fe transpose: fe[b][c][v] (f32) -> feT[b][v][c] (f16) ----
__global__ __launch_bounds__(256) void transpose_fe(const float* __restrict__ fe,
                                                    u16* __restrict__ feT) {
    __shared__ u16 tile[32][33];
    const int t  = threadIdx.x;
    const int tx = t & 31, ty = t >> 5;           // 32 x 8
    const int v0 = blockIdx.x * 32;
    const int c0 = blockIdx.y * 32;
    const int b  = blockIdx.z;
#pragma unroll
    for (int p = 0; p < 4; ++p) {
        const int c = c0 + ty + p * 8;
        const int v = v0 + tx;
        if (v < V) tile[ty + p * 8][tx] = f2h(fe[((size_t)b * CIN + c) * V + v]);
    }
    __syncthreads();
#pragma unroll
    for (int p = 0; p < 4; ++p) {
        const int v = v0 + ty + p * 8;
        const int c = c0 + tx;
        if (v < V) feT[((size_t)b * V + v) * CIN + c] = tile[tx][ty + p * 8];
    }
}

// ---- MFMA gather-conv: 64-channel stages, 2 LDS buffers, counted-wait barriers.
// Block = 128o x 128v; waves 2x2, wave tile 64o x 64v; 32 MFMA per barrier.
// INL:  0 = vertex-major f16 [B][V][C]; 1 = channel-major f32 [B][C][V]
// OUTL: 0 = vertex-major f16 [B][V][COUT] (ws); 1 = channel-major f32 (d_out)
// Fuses instance-norm partial stats (sum, sumsq) into P.
template<int C, int INL, int OUTL>
__global__ __launch_bounds__(256, 2) void conv_mfma(const void* __restrict__ xin_,
                                                    const u16*  __restrict__ wF,
                                                    const float* __restrict__ bias,
                                                    const int*  __restrict__ nbr,
                                                    void* __restrict__ out_,
                                                    float2* __restrict__ P) {
    constexpr int NS = KP1 * C / 64;     // 7 or 14 stages (64 ch each)
    __shared__ __align__(16) u16 Xl[2][BN][72];   // 144B rows: conflict-free b128 r/w
    __shared__ float2 Sred[4][COUT];

    const int t    = threadIdx.x;
    const int b    = blockIdx.x / NT;
    const int tile = blockIdx.x % NT;
    const int v0   = tile * BN;
    const int w    = t >> 6;
    const int l    = t & 63;
    const int wo   = (w & 1) * 64;       // wave o-offset
    const int wv   = (w >> 1) * 64;      // wave v-offset

    // staging role: row sv = t>>1 (0..127), 64B half h = t&1
    const int sv = t >> 1;
    const int h  = t & 1;
    const int vS = v0 + sv;
    int idxS[KP1];
    {
        const int vc = (vS < V) ? vS : 0;
        idxS[0] = vc;
#pragma unroll
        for (int k = 1; k < KP1; ++k)
            idxS[k] = nbr[((size_t)b * V + vc) * 6 + (k - 1)];
    }

    // consumer vertices
    int vn[4]; bool ok[4];
#pragma unroll
    for (int n = 0; n < 4; ++n) {
        vn[n] = v0 + wv + n * 16 + (l & 15);
        ok[n] = vn[n] < V;
    }

    f32x4 acc[4][4];
#pragma unroll
    for (int m = 0; m < 4; ++m)
#pragma unroll
        for (int n = 0; n < 4; ++n) acc[m][n] = (f32x4)0.f;

    u16x8 g[2][4];    // gather regs: 64B per thread per stage, 2 sets
    f16x8 af[2][8];   // weight frags: (kc*4+m), double-buffered

    auto gload = [&](auto SC, u16x8 (&gr)[4]) {
        constexpr int S    = decltype(SC)::value;
        constexpr int k_   = (C == 64) ? S : (S >> 1);
        constexpr int off_ = (C == 64) ? 0 : (S & 1) * 64;
        if constexpr (INL == 0) {
            const u16* x_ = (const u16*)xin_;
            const u16* p_ = &x_[((size_t)b * V + idxS[k_]) * C + off_ + h * 32];
#pragma unroll
            for (int j = 0; j < 4; ++j) gr[j] = *(const u16x8*)(p_ + j * 8);
        } else {
            const float* x_ = (const float*)xin_;
#pragma unroll
            for (int j = 0; j < 32; ++j) {
                const float v_ = x_[((size_t)b * C + off_ + h * 32 + j) * V + idxS[k_]];
                gr[j >> 3][j & 7] = f2h(v_);
            }
        }
    };
    auto aload = [&](auto SC, f16x8 (&ar)[8]) {
        constexpr int S = decltype(SC)::value;
#pragma unroll
        for (int kc = 0; kc < 2; ++kc)
#pragma unroll
            for (int m = 0; m < 4; ++m)
                ar[kc * 4 + m] =
                    *(const f16x8*)&wF[(((size_t)(2 * S + kc) * 8 + (wo >> 4) + m) * 64 + l) * 8];
    };
    auto store = [&](int bufi, u16x8 (&gr)[4]) {
#pragma unroll
        for (int j = 0; j < 4; ++j)
            *(u16x8*)&Xl[bufi][sv][h * 32 + j * 8] = gr[j];
    };

    // prologue: stage0 -> buf0; stage1 -> g[1]; af(0)
    gload(std::integral_constant<int, 0>{}, g[0]);
    if constexpr (NS > 1) gload(std::integral_constant<int, 1>{}, g[1]);
    aload(std::integral_constant<int, 0>{}, af[0]);
    store(0, g[0]);
    asm volatile("s_waitcnt lgkmcnt(0)" ::: "memory");
    __builtin_amdgcn_s_barrier();

    static_for<NS>([&](auto SC) {
        constexpr int s = decltype(SC)::value;
        // 1. bf reads from current buffer
        f16x8 bf[4][2];
#pragma unroll
        for (int n = 0; n < 4; ++n)
#pragma unroll
            for (int kc = 0; kc < 2; ++kc)
                bf[n][kc] = *(const f16x8*)&Xl[s & 1][wv + n * 16 + (l & 15)]
                                              [kc * 32 + (l >> 4) * 8];
        // 2. issue gather for stage s+2 (consumed by store at iter s+1)
        if constexpr (s + 2 < NS)
            gload(std::integral_constant<int, s + 2>{}, g[s & 1]);
        // 3. issue af for stage s+1
        if constexpr (s + 1 < NS)
            aload(std::integral_constant<int, s + 1>{}, af[(s + 1) & 1]);
        // 4. 32 MFMA
#pragma unroll
        for (int kc = 0; kc < 2; ++kc)
#pragma unroll
            for (int m = 0; m < 4; ++m)
#pragma unroll
                for (int n = 0; n < 4; ++n)
                    acc[m][n] = __builtin_amdgcn_mfma_f32_16x16x32_f16(af[s & 1][kc * 4 + m],
                                                                       bf[n][kc],
                                                                       acc[m][n], 0, 0, 0);
        // 5. write next stage to the other buffer (vmcnt stall lands after MFMAs)
        if constexpr (s + 1 < NS) {
            __builtin_amdgcn_sched_barrier(0);
            store((s + 1) & 1, g[(s + 1) & 1]);
            asm volatile("s_waitcnt lgkmcnt(0)" ::: "memory");
            __builtin_amdgcn_s_barrier();
        }
    });

    // D layout: o = wo + m*16 + (l>>4)*4 + q ; v = vn[n]
    if constexpr (OUTL == 0) {
        u16* po = (u16*)out_;
#pragma unroll
        for (int n = 0; n < 4; ++n) {
            if (ok[n]) {
#pragma unroll
                for (int m = 0; m < 4; ++m) {
                    const int o = wo + m * 16 + ((l >> 4) << 2);
                    u16x4 pk;
#pragma unroll
                    for (int q = 0; q < 4; ++q) pk[q] = f2h(acc[m][n][q] + bias[o + q]);
                    *(u16x4*)&po[((size_t)b * V + vn[n]) * COUT + o] = pk;
                }
            }
        }
    } else {
        float* po = (float*)out_;
#pragma unroll
        for (int m = 0; m < 4; ++m) {
            const int o = wo + m * 16 + ((l >> 4) << 2);
#pragma unroll
            for (int q = 0; q < 4; ++q) {
                const float bq = bias[o + q];
#pragma unroll
                for (int n = 0; n < 4; ++n)
                    if (ok[n]) po[((size_t)(b * COUT + o + q)) * V + vn[n]] = acc[m][n][q] + bq;
            }
        }
    }

    // fused instance-norm partials
#pragma unroll
    for (int m = 0; m < 4; ++m) {
        const int o = wo + m * 16 + ((l >> 4) << 2);
        float s[4], s2[4];
#pragma unroll
        for (int q = 0; q < 4; ++q) {
            const float bq = bias[o + q];
            float a = 0.f, aa = 0.f;
#pragma unroll
            for (int n = 0; n < 4; ++n) {
                if (ok[n]) {
                    const float val = acc[m][n][q] + bq;
                    a += val; aa += val * val;
                }
            }
            s[q] = a; s2[q] = aa;
        }
#pragma unroll
        for (int d = 1; d < 16; d <<= 1) {
#pragma unroll
            for (int q = 0; q < 4; ++q) {
                s[q]  += __shfl_xor(s[q],  d, 16);
                s2[q] += __shfl_xor(s2[q], d, 16);
            }
        }
        if ((l & 15) == 0) {
#pragma unroll
            for (int q = 0; q < 4; ++q)
                Sred[w][o + q] = make_float2(s[q], s2[q]);
        }
    }
    __syncthreads();
    if (t < COUT) {
        const int wlo = t >> 6;            // o-half -> waves wlo and wlo+2
        const float2 a = Sred[wlo][t];
        const float2 c = Sred[wlo + 2][t];
        P[((size_t)b * COUT + t) * NTP + tile] = make_float2(a.x + c.x, a.y + c.y);
    }
}

// ---- finalize fused partials: S[row] = (mean, rsqrt(var+eps)) ----
__global__ __launch_bounds__(256) void finalize_fused(const float2* __restrict__ P,
                                                      float2* __restrict__ S) {
    const int row = blockIdx.x;       // B*COUT
    float s = 0.f, s2 = 0.f;
    for (int i = threadIdx.x; i < NT; i += 256) {
        const float2 p = P[(size_t)row * NTP + i];
        s += p.x; s2 += p.y;
    }
    __shared__ float2 red[256];
    red[threadIdx.x] = make_float2(s, s2);
    __syncthreads();
    for (int w = 128; w > 0; w >>= 1) {
        if (threadIdx.x < w) {
            red[threadIdx.x].x += red[threadIdx.x + w].x;
            red[threadIdx.x].y += red[threadIdx.x + w].y;
        }
        __syncthreads();
    }
    if (threadIdx.x == 0) {
        const float m = red[0].x / V;
        const float var = red[0].y / V - m * m;
        S[row] = make_float2(m, rsqrtf(var + EPS));
    }
}

// ---- normalize + relu in place, vertex-major f16 (ws) ----
__global__ __launch_bounds__(256) void norm1(u16* __restrict__ x,
                                             const float2* __restrict__ S) {
    const unsigned e = ((unsigned)blockIdx.x * 256u + threadIdx.x) * 8u;
    if (e >= (unsigned)B * V * COUT) return;
    const unsigned b  = e / ((unsigned)V * COUT);
    const unsigned o0 = e & 127u;
    u16x8 vv = *(u16x8*)&x[e];
#pragma unroll
    for (int j = 0; j < 8; ++j) {
        const float2 s = S[b * COUT + o0 + j];
        float f = (h2f(vv[j]) - s.x) * s.y;
        vv[j] = f2h(fmaxf(f, 0.f));
    }
    *(u16x8*)&x[e] = vv;
}

// ---- final (full tier): y2,x1 vertex-major f16 -> out channel-major f32 ----
__global__ __launch_bounds__(256) void final_mix2(const u16* __restrict__ y2,
                                                  const u16* __restrict__ x1,
                                                  const float2* __restrict__ S,
                                                  float* __restrict__ out) {
    __shared__ float ty[64][33], tx[64][33];
    const int t  = threadIdx.x;
    const int v0 = blockIdx.x * 64;
    const int o0 = blockIdx.y * 32;
    const int b  = blockIdx.z;
    const int jr = (t & 7) * 4;
    const int ir = t >> 3;             // 0..31
#pragma unroll
    for (int p = 0; p < 2; ++p) {
        const int i = ir + p * 32;
        const int v = v0 + i;
        if (v < V) {
            const size_t base = ((size_t)b * V + v) * COUT + o0 + jr;
            const u16x4 a = *(const u16x4*)&y2[base];
            const u16x4 c = *(const u16x4*)&x1[base];
#pragma unroll
            for (int q = 0; q < 4; ++q) {
                ty[i][jr + q] = h2f(a[q]);
                tx[i][jr + q] = h2f(c[q]);
            }
        }
    }
    __syncthreads();
    const int vl = t & 63, v = v0 + vl, oo0 = t >> 6;
    if (v < V) {
#pragma unroll
        for (int p = 0; p < 8; ++p) {
            const int oo = oo0 + p * 4;
            const int o  = o0 + oo;
            const float2 s = S[b * COUT + o];
            out[((size_t)b * COUT + o) * V + v] =
                fmaxf((ty[vl][oo] - s.x) * s.y + tx[vl][oo], 0.f);
        }
    }
}

// ---- final (fallback tier): y f32 CM in place; x1 f16 VM staged via LDS ----
__global__ __launch_bounds__(256) void final_mix(float* __restrict__ y,
                                                 const u16* __restrict__ x1,
                                                 const float2* __restrict__ S) {
    __shared__ float tile[64][33];
    const int t  = threadIdx.x;
    const int v0 = blockIdx.x * 64;
    const int o0 = blockIdx.y * 32;
    const int b  = blockIdx.z;
    const int j  = t & 31;
    const int i0 = t >> 5;
#pragma unroll
    for (int p = 0; p < 8; ++p) {
        const int i = i0 + p * 8;
        const int v = v0 + i;
        tile[i][j] = (v < V) ? h2f(x1[((size_t)b * V + v) * COUT + o0 + j]) : 0.f;
    }
    __syncthreads();
    const int vl  = t & 63;
    const int v   = v0 + vl;
    const int oo0 = t >> 6;
    if (v < V) {
#pragma unroll
        for (int p = 0; p < 8; ++p) {
            const int oo = oo0 + p * 4;
            const int o  = o0 + oo;
            const size_t idx = ((size_t)b * COUT + o) * V + v;
            const float2 s = S[b * COUT + o];
            const float f = (y[idx] - s.x) * s.y + tile[vl][oo];
            y[idx] = fmaxf(f, 0.f);
        }
    }
}

extern "C" void kernel_launch(void* const* d_in, const int* in_sizes, int n_in,
                              void* d_out, int out_size, void* d_ws, size_t ws_size,
                              hipStream_t stream) {
    const float* fe  = (const float*)d_in[0];
    const int*   nbr = (const int*)d_in[1];
    const float* w1  = (const float*)d_in[2];
    const float* b1  = (const float*)d_in[3];
    const float* w2  = (const float*)d_in[4];
    const float* b2  = (const float*)d_in[5];
    float* outf = (float*)d_out;
    char*  ws   = (char*)d_ws;

    constexpr size_t wF1_b = (size_t)(KP1 * CIN  / 32) * 8 * 64 * 8 * 2;  // 112 KB
    constexpr size_t wF2_b = (size_t)(KP1 * COUT / 32) * 8 * 64 * 8 * 2;  // 224 KB
    constexpr size_t S_b   = (size_t)B * COUT * 8;
    constexpr size_t Pf_b  = (size_t)B * COUT * NTP * 8;  // 1.6 MB
    constexpr size_t x1_b  = (size_t)B * V * COUT * 2;    // 51.2 MB
    constexpr size_t y2_b  = (size_t)B * V * COUT * 2;    // 51.2 MB
    constexpr size_t feT_b = (size_t)B * V * CIN * 2;     // 25.6 MB
    const size_t base = wF1_b + wF2_b + 2 * S_b + Pf_b;

    // tiers: full (y2 overlays feT region), T3 (feT, f32-CM out), T4 (minimal)
    const bool full = (ws_size >= base + x1_b + y2_b);    // ~104.4 MB
    const bool t3   = (ws_size >= base + x1_b + feT_b);   // ~78.8 MB
    const bool t4   = (ws_size >= base + x1_b);           // ~53.2 MB
    if (!full && !t3 && !t4) return;

    size_t off = 0;
    u16*    wF1 = (u16*)(ws + off);    off += wF1_b;
    u16*    wF2 = (u16*)(ws + off);    off += wF2_b;
    float2* S1  = (float2*)(ws + off); off += S_b;
    float2* S2  = (float2*)(ws + off); off += S_b;
    float2* P   = (float2*)(ws + off); off += Pf_b;
    u16*    x1  = (u16*)(ws + off);    off += x1_b;
    u16*    ext = (u16*)(ws + off);    // feT and/or y2 region

    prep_wf<CIN> <<<(KP1 * CIN  / 32) * 8 * 64 / 256, 256, 0, stream>>>(w1, wF1);
    prep_wf<COUT><<<(KP1 * COUT / 32) * 8 * 64 / 256, 256, 0, stream>>>(w2, wF2);

    const bool useFeT = full || t3;
    if (useFeT) {
        dim3 gt((V + 31) / 32, CIN / 32, B);
        transpose_fe<<<gt, 256, 0, stream>>>(fe, ext);   // feT at ext
    }

    if (useFeT) conv_mfma<CIN, 0, 0><<<B * NT, 256, 0, stream>>>(ext, wF1, b1, nbr, x1, P);
    else        conv_mfma<CIN, 1, 0><<<B * NT, 256, 0, stream>>>(fe,  wF1, b1, nbr, x1, P);
    finalize_fused<<<B * COUT, 256, 0, stream>>>(P, S1);
    norm1<<<(int)((size_t)B * V * COUT / 8 / 256), 256, 0, stream>>>(x1, S1);

    dim3 gf(NT64, COUT / 32, B);
    if (full) {
        u16* y2 = ext;   // overlays feT (dead after conv1)
        conv_mfma<COUT, 0, 0><<<B * NT, 256, 0, stream>>>(x1, wF2, b2, nbr, y2, P);
        finalize_fused<<<B * COUT, 256, 0, stream>>>(P, S2);
        final_mix2<<<gf, 256, 0, stream>>>(y2, x1, S2, outf);
    } else {
        conv_mfma<COUT, 0, 1><<<B * NT, 256, 0, stream>>>(x1, wF2, b2, nbr, outf, P);
        finalize_fused<<<B * COUT, 256, 0, stream>>>(P, S2);
        final_mix<<<gf, 256, 0, stream>>>(outf, x1, S2);
    }
}